// Round 1
// baseline (891.493 us; speedup 1.0000x reference)
//
#include <hip/hip_runtime.h>
#include <math.h>

// GAT 2-layer + BN + classifier, fp32, MI355X.
// Structure: CSR build (count/scan/fill) -> GEMM1 -> alpha -> aggregate ->
// BN stats -> GEMM2(fused BN+relu) -> alpha -> aggregate -> BN stats ->
// classifier GEMM (fused BN+relu). BN-normalized activations never materialized.

#define CDIM 128
#define NCLS_ 40
#define NEG_SLOPE_ 0.2f
#define BN_EPS_ 1e-5f

static __device__ __forceinline__ float lrelu(float a) {
    return a > 0.f ? a : NEG_SLOPE_ * a;
}

// ---------------- init: deg=1 (self loop), cursor=0, bn sums zero ----------
__global__ void k_init(int* deg, int* cursor, float* bnsum, int n) {
    int i = blockIdx.x * blockDim.x + threadIdx.x;
    if (i < n) { deg[i] = 1; cursor[i] = 0; }
    if (i < 512) bnsum[i] = 0.f;
}

// ---------------- degree histogram over input edges ------------------------
__global__ void k_count(const int* __restrict__ dst, int E, int* __restrict__ deg) {
    int e = blockIdx.x * blockDim.x + threadIdx.x;
    if (e < E) atomicAdd(&deg[dst[e]], 1);
}

// ---------------- exclusive scan (1024-elem chunks) ------------------------
__global__ void k_scan1(const int* __restrict__ deg, int* __restrict__ offs,
                        int* __restrict__ partial, int n) {
    __shared__ int sdata[256];
    int tid = threadIdx.x;
    int base = blockIdx.x * 1024 + tid * 4;
    int v[4]; int s = 0;
    for (int j = 0; j < 4; j++) { int idx = base + j; v[j] = (idx < n) ? deg[idx] : 0; s += v[j]; }
    sdata[tid] = s; __syncthreads();
    for (int d = 1; d < 256; d <<= 1) {
        int t = (tid >= d) ? sdata[tid - d] : 0;
        __syncthreads();
        sdata[tid] += t;
        __syncthreads();
    }
    int excl = sdata[tid] - s;
    if (tid == 255) partial[blockIdx.x] = sdata[255];
    int run = excl;
    for (int j = 0; j < 4; j++) { int idx = base + j; if (idx < n) offs[idx] = run; run += v[j]; }
}

__global__ void k_scan2(int* partial, int nb) {
    __shared__ int sdata[128];
    int t = threadIdx.x;
    int v = (t < nb) ? partial[t] : 0;
    sdata[t] = v; __syncthreads();
    for (int d = 1; d < 128; d <<= 1) {
        int x = (t >= d) ? sdata[t - d] : 0;
        __syncthreads();
        sdata[t] += x;
        __syncthreads();
    }
    if (t < nb) partial[t] = sdata[t] - v;   // exclusive
}

__global__ void k_scan3(int* __restrict__ offs, const int* __restrict__ partial,
                        int n, int total) {
    int i = blockIdx.x * blockDim.x + threadIdx.x;
    if (i < n) offs[i] += partial[i >> 10];
    if (i == 0) offs[n] = total;
}

// ---------------- CSR fill (input edges + self loops) ----------------------
__global__ void k_fill(const int* __restrict__ src, const int* __restrict__ dst,
                       int E, int n, const int* __restrict__ offs,
                       int* __restrict__ cursor, int* __restrict__ csr) {
    int e = blockIdx.x * blockDim.x + threadIdx.x;
    if (e < E) {
        int d = dst[e];
        int p = offs[d] + atomicAdd(&cursor[d], 1);
        csr[p] = src[e];
    } else if (e < E + n) {
        int i = e - E;
        int p = offs[i] + atomicAdd(&cursor[i], 1);
        csr[p] = i;
    }
}

// ---------------- GEMM: H = act(X) @ W,  K=C=128, 64x64 tile ---------------
// fuse==1: act(x) = relu(x*scale[k]+shift[k])  (BN+relu fused on load)
#define XS_LD 132
#define WS_LD 68
__global__ __launch_bounds__(256, 2) void k_gemm128(
    const float* __restrict__ X, const float* __restrict__ W,
    const float* __restrict__ scale, const float* __restrict__ shift,
    float* __restrict__ H, int n, int fuse)
{
    __shared__ float Xs[64 * XS_LD];    // 33.8 KB
    __shared__ float Ws[128 * WS_LD];   // 34.8 KB  -> 2 blocks/CU
    int t = threadIdx.x;
    int row0 = blockIdx.x * 64;
    int col0 = blockIdx.y * 64;

    // stage W tile: 128 k x 64 cols
    for (int j = 0; j < 8; j++) {
        int idx = j * 256 + t;          // 2048 float4
        int k = idx >> 4, c4 = idx & 15;
        float4 w = *(const float4*)(W + (size_t)k * CDIM + col0 + c4 * 4);
        *(float4*)(Ws + k * WS_LD + c4 * 4) = w;
    }
    // stage X tile: 64 rows x 128 k, optional BN+relu
    for (int j = 0; j < 8; j++) {
        int idx = j * 256 + t;          // 2048 float4
        int r = idx >> 5, k4 = idx & 31;
        int gr = row0 + r;
        float4 xv = make_float4(0.f, 0.f, 0.f, 0.f);
        if (gr < n) xv = *(const float4*)(X + (size_t)gr * CDIM + k4 * 4);
        if (fuse) {
            float4 sc = *(const float4*)(scale + k4 * 4);
            float4 sh = *(const float4*)(shift + k4 * 4);
            xv.x = fmaxf(fmaf(xv.x, sc.x, sh.x), 0.f);
            xv.y = fmaxf(fmaf(xv.y, sc.y, sh.y), 0.f);
            xv.z = fmaxf(fmaf(xv.z, sc.z, sh.z), 0.f);
            xv.w = fmaxf(fmaf(xv.w, sc.w, sh.w), 0.f);
        }
        *(float4*)(Xs + r * XS_LD + k4 * 4) = xv;
    }
    __syncthreads();

    int colg = t & 15, rowg = t >> 4;   // 16 col-groups x 16 row-groups
    float acc[4][4] = {};
    for (int k = 0; k < CDIM; k++) {
        float4 w = *(const float4*)(Ws + k * WS_LD + colg * 4);
        float x0 = Xs[(rowg * 4 + 0) * XS_LD + k];
        float x1 = Xs[(rowg * 4 + 1) * XS_LD + k];
        float x2 = Xs[(rowg * 4 + 2) * XS_LD + k];
        float x3 = Xs[(rowg * 4 + 3) * XS_LD + k];
        acc[0][0] = fmaf(x0, w.x, acc[0][0]); acc[0][1] = fmaf(x0, w.y, acc[0][1]);
        acc[0][2] = fmaf(x0, w.z, acc[0][2]); acc[0][3] = fmaf(x0, w.w, acc[0][3]);
        acc[1][0] = fmaf(x1, w.x, acc[1][0]); acc[1][1] = fmaf(x1, w.y, acc[1][1]);
        acc[1][2] = fmaf(x1, w.z, acc[1][2]); acc[1][3] = fmaf(x1, w.w, acc[1][3]);
        acc[2][0] = fmaf(x2, w.x, acc[2][0]); acc[2][1] = fmaf(x2, w.y, acc[2][1]);
        acc[2][2] = fmaf(x2, w.z, acc[2][2]); acc[2][3] = fmaf(x2, w.w, acc[2][3]);
        acc[3][0] = fmaf(x3, w.x, acc[3][0]); acc[3][1] = fmaf(x3, w.y, acc[3][1]);
        acc[3][2] = fmaf(x3, w.z, acc[3][2]); acc[3][3] = fmaf(x3, w.w, acc[3][3]);
    }
    for (int i = 0; i < 4; i++) {
        int gr = row0 + rowg * 4 + i;
        if (gr < n) {
            float4 o = make_float4(acc[i][0], acc[i][1], acc[i][2], acc[i][3]);
            *(float4*)(H + (size_t)gr * CDIM + col0 + colg * 4) = o;
        }
    }
}

// ---------------- per-node attention dot products --------------------------
__global__ void k_alpha(const float* __restrict__ H, const float* __restrict__ avs,
                        const float* __restrict__ avd, float* __restrict__ alpha_s,
                        float* __restrict__ alpha_d, int n) {
    int wave = blockIdx.x * 4 + (threadIdx.x >> 6);
    int lane = threadIdx.x & 63;
    if (wave >= n) return;
    float2 h = *(const float2*)(H + (size_t)wave * CDIM + lane * 2);
    float2 a = *(const float2*)(avs + lane * 2);
    float2 d = *(const float2*)(avd + lane * 2);
    float ps = h.x * a.x + h.y * a.y;
    float pd = h.x * d.x + h.y * d.y;
    for (int o = 32; o > 0; o >>= 1) {
        ps += __shfl_xor(ps, o);
        pd += __shfl_xor(pd, o);
    }
    if (lane == 0) { alpha_s[wave] = ps; alpha_d[wave] = pd; }
}

// ---------------- per-node softmax + aggregation (one wave per node) -------
__global__ __launch_bounds__(256) void k_agg(
    const float* __restrict__ H, const int* __restrict__ offs,
    const int* __restrict__ csr, const float* __restrict__ alpha_s,
    const float* __restrict__ alpha_d, const float* __restrict__ bias,
    float* __restrict__ O, int n)
{
    int i = blockIdx.x * 4 + (threadIdx.x >> 6);
    int lane = threadIdx.x & 63;
    if (i >= n) return;
    int o0 = offs[i], o1 = offs[i + 1];
    float adi = alpha_d[i];

    // pass 1: segment max
    float m = -1e30f;
    for (int j = o0 + lane; j < o1; j += 64) {
        float a = lrelu(alpha_s[csr[j]] + adi);
        m = fmaxf(m, a);
    }
    for (int o = 32; o > 0; o >>= 1) m = fmaxf(m, __shfl_xor(m, o));

    // pass 2: segment sum of exp
    float se = 0.f;
    for (int j = o0 + lane; j < o1; j += 64) {
        float a = lrelu(alpha_s[csr[j]] + adi);
        se += __expf(a - m);
    }
    for (int o = 32; o > 0; o >>= 1) se += __shfl_xor(se, o);
    float inv = 1.f / se;

    // pass 3: weighted gather-accumulate, 2 channels/lane, 1-deep pipeline
    const float2* H2 = (const float2*)H;
    float2 acc = make_float2(0.f, 0.f);
    int s0 = csr[o0];
    float2 h0 = H2[(size_t)s0 * 64 + lane];
    for (int j = o0; j < o1 - 1; ++j) {
        int s1 = csr[j + 1];
        float2 h1 = H2[(size_t)s1 * 64 + lane];
        float w = __expf(lrelu(alpha_s[s0] + adi) - m) * inv;
        acc.x = fmaf(w, h0.x, acc.x);
        acc.y = fmaf(w, h0.y, acc.y);
        s0 = s1; h0 = h1;
    }
    {
        float w = __expf(lrelu(alpha_s[s0] + adi) - m) * inv;
        acc.x = fmaf(w, h0.x, acc.x);
        acc.y = fmaf(w, h0.y, acc.y);
    }
    float2 b = *(const float2*)(bias + lane * 2);
    *(float2*)(O + (size_t)i * CDIM + lane * 2) = make_float2(acc.x + b.x, acc.y + b.y);
}

// ---------------- BN stats: per-channel sum / sumsq ------------------------
__global__ void k_bnstats(const float* __restrict__ H, int n, float* __restrict__ sums) {
    __shared__ float ls[256], ls2[256];
    int c = threadIdx.x & 127;
    int half = threadIdx.x >> 7;
    float s = 0.f, s2 = 0.f;
    for (int r = blockIdx.x * 2 + half; r < n; r += gridDim.x * 2) {
        float v = H[(size_t)r * CDIM + c];
        s += v; s2 += v * v;
    }
    ls[threadIdx.x] = s; ls2[threadIdx.x] = s2;
    __syncthreads();
    if (threadIdx.x < 128) {
        atomicAdd(&sums[c], ls[threadIdx.x] + ls[threadIdx.x + 128]);
        atomicAdd(&sums[128 + c], ls2[threadIdx.x] + ls2[threadIdx.x + 128]);
    }
}

__global__ void k_bnfin(const float* __restrict__ sums, const float* __restrict__ gamma,
                        const float* __restrict__ beta, float* __restrict__ scale,
                        float* __restrict__ shift, int n) {
    int c = threadIdx.x;   // 128 threads
    float invn = 1.f / (float)n;
    float mean = sums[c] * invn;
    float var = fmaxf(sums[128 + c] * invn - mean * mean, 0.f);
    float sc = gamma[c] * rsqrtf(var + BN_EPS_);
    scale[c] = sc;
    shift[c] = beta[c] - mean * sc;
}

// ---------------- classifier: out = relu(bn(G)) @ Wc + bc ------------------
#define CLS_XS_LD 129
__global__ __launch_bounds__(256) void k_cls(
    const float* __restrict__ G, const float* __restrict__ Wc,
    const float* __restrict__ bc, const float* __restrict__ scale,
    const float* __restrict__ shift, float* __restrict__ out, int n)
{
    __shared__ float Xs[128 * CLS_XS_LD];   // 66.0 KB
    __shared__ float Ws[128 * NCLS_];       // 20.5 KB
    int t = threadIdx.x;
    int row0 = blockIdx.x * 128;

    for (int j = 0; j < 20; j++) Ws[j * 256 + t] = Wc[j * 256 + t];  // 5120 floats
    for (int j = 0; j < 16; j++) {
        int idx = j * 256 + t;              // 4096 float4 = 128 rows x 32
        int r = idx >> 5, k4 = idx & 31;
        int gr = row0 + r;
        float4 xv = make_float4(0.f, 0.f, 0.f, 0.f);
        if (gr < n) xv = *(const float4*)(G + (size_t)gr * CDIM + k4 * 4);
        float4 sc = *(const float4*)(scale + k4 * 4);
        float4 sh = *(const float4*)(shift + k4 * 4);
        float* xp = Xs + r * CLS_XS_LD + k4 * 4;
        xp[0] = fmaxf(fmaf(xv.x, sc.x, sh.x), 0.f);
        xp[1] = fmaxf(fmaf(xv.y, sc.y, sh.y), 0.f);
        xp[2] = fmaxf(fmaf(xv.z, sc.z, sh.z), 0.f);
        xp[3] = fmaxf(fmaf(xv.w, sc.w, sh.w), 0.f);
    }
    __syncthreads();

    int cg = t & 3;        // 4 col groups x 10 cols
    int r0 = t >> 2;       // 64 row groups x 2 rows
    float acc[2][10] = {};
    for (int k = 0; k < CDIM; k++) {
        float x0 = Xs[(r0 * 2 + 0) * CLS_XS_LD + k];
        float x1 = Xs[(r0 * 2 + 1) * CLS_XS_LD + k];
        #pragma unroll
        for (int j = 0; j < 10; j++) {
            float w = Ws[k * NCLS_ + cg * 10 + j];
            acc[0][j] = fmaf(x0, w, acc[0][j]);
            acc[1][j] = fmaf(x1, w, acc[1][j]);
        }
    }
    for (int i = 0; i < 2; i++) {
        int gr = row0 + r0 * 2 + i;
        if (gr < n) {
            #pragma unroll
            for (int j = 0; j < 10; j++)
                out[(size_t)gr * NCLS_ + cg * 10 + j] = acc[i][j] + bc[cg * 10 + j];
        }
    }
}

// ---------------- launch ---------------------------------------------------
extern "C" void kernel_launch(void* const* d_in, const int* in_sizes, int n_in,
                              void* d_out, int out_size, void* d_ws, size_t ws_size,
                              hipStream_t stream)
{
    const float* x   = (const float*)d_in[0];
    const int*   ei  = (const int*)d_in[1];
    const float* W1  = (const float*)d_in[2];
    const float* as1 = (const float*)d_in[3];
    const float* ad1 = (const float*)d_in[4];
    const float* b1  = (const float*)d_in[5];
    const float* g1  = (const float*)d_in[6];
    const float* be1 = (const float*)d_in[7];
    const float* W2  = (const float*)d_in[8];
    const float* as2 = (const float*)d_in[9];
    const float* ad2 = (const float*)d_in[10];
    const float* b2  = (const float*)d_in[11];
    const float* g2  = (const float*)d_in[12];
    const float* be2 = (const float*)d_in[13];
    const float* Wc  = (const float*)d_in[14];
    const float* bc  = (const float*)d_in[15];
    float* out = (float*)d_out;

    int n = in_sizes[0] / CDIM;     // 100000
    int E = in_sizes[1] / 2;        // 1600000
    const int* src = ei;
    const int* dst = ei + E;

    // workspace layout (~112 MB)
    float* bufA    = (float*)d_ws;
    float* bufB    = bufA + (size_t)n * CDIM;
    float* alpha_s = bufB + (size_t)n * CDIM;
    float* alpha_d = alpha_s + n;
    float* bnsum   = alpha_d + n;       // 512 (two layers' sum/sumsq)
    float* scale1  = bnsum + 512;
    float* shift1  = scale1 + 128;
    float* scale2  = shift1 + 128;
    float* shift2  = scale2 + 128;
    int* deg     = (int*)(shift2 + 128);
    int* cursor  = deg + n;
    int* offs    = cursor + n;          // n+1
    int* partial = offs + (n + 1);      // 128
    int* csr     = partial + 128;       // E + n

    int nb = (n + 1023) / 1024;

    k_init<<<dim3((n + 255) / 256), dim3(256), 0, stream>>>(deg, cursor, bnsum, n);
    k_count<<<dim3((E + 255) / 256), dim3(256), 0, stream>>>(dst, E, deg);
    k_scan1<<<dim3(nb), dim3(256), 0, stream>>>(deg, offs, partial, n);
    k_scan2<<<dim3(1), dim3(128), 0, stream>>>(partial, nb);
    k_scan3<<<dim3((n + 255) / 256), dim3(256), 0, stream>>>(offs, partial, n, E + n);
    k_fill<<<dim3((E + n + 255) / 256), dim3(256), 0, stream>>>(src, dst, E, n, offs, cursor, csr);

    dim3 ggrid((n + 63) / 64, 2);
    dim3 wgrid((n + 3) / 4);

    // layer 1
    k_gemm128<<<ggrid, 256, 0, stream>>>(x, W1, nullptr, nullptr, bufA, n, 0);
    k_alpha<<<wgrid, 256, 0, stream>>>(bufA, as1, ad1, alpha_s, alpha_d, n);
    k_agg<<<wgrid, 256, 0, stream>>>(bufA, offs, csr, alpha_s, alpha_d, b1, bufB, n);
    k_bnstats<<<dim3(256), dim3(256), 0, stream>>>(bufB, n, bnsum);
    k_bnfin<<<dim3(1), dim3(128), 0, stream>>>(bnsum, g1, be1, scale1, shift1, n);

    // layer 2 (BN1+relu fused into GEMM2 load)
    k_gemm128<<<ggrid, 256, 0, stream>>>(bufB, W2, scale1, shift1, bufA, n, 1);
    k_alpha<<<wgrid, 256, 0, stream>>>(bufA, as2, ad2, alpha_s, alpha_d, n);
    k_agg<<<wgrid, 256, 0, stream>>>(bufA, offs, csr, alpha_s, alpha_d, b2, bufB, n);
    k_bnstats<<<dim3(256), dim3(256), 0, stream>>>(bufB, n, bnsum + 256);
    k_bnfin<<<dim3(1), dim3(128), 0, stream>>>(bnsum + 256, g2, be2, scale2, shift2, n);

    // classifier (BN2+relu fused into load)
    k_cls<<<dim3((n + 127) / 128), dim3(256), 0, stream>>>(bufB, Wc, bc, scale2, shift2, out, n);
}

// Round 2
// 778.353 us; speedup vs baseline: 1.1454x; 1.1454x over previous
//
#include <hip/hip_runtime.h>
#include <math.h>

// GAT 2-layer + BN + classifier, MI355X.
// R2: bf16-MFMA GEMMs with fused alpha epilogue + bf16 H for the gather,
// parallel edge-weight computation in k_agg (shuffle-broadcast inner loop).

#define CDIM 128
#define NCLS_ 40
#define NEG_SLOPE_ 0.2f
#define BN_EPS_ 1e-5f

using short8  = __attribute__((ext_vector_type(8))) short;
using short4v = __attribute__((ext_vector_type(4))) short;
using f32x4   = __attribute__((ext_vector_type(4))) float;

static __device__ __forceinline__ float lrelu(float a) {
    return a > 0.f ? a : NEG_SLOPE_ * a;
}
// fp32 -> bf16 round-to-nearest-even
static __device__ __forceinline__ short f2bf(float f) {
    unsigned u = __float_as_uint(f);
    u += 0x7fffu + ((u >> 16) & 1u);
    return (short)(u >> 16);
}

// ---------------- init: deg=1 (self loop), cursor=0, bn sums zero ----------
__global__ void k_init(int* deg, int* cursor, float* bnsum, int n) {
    int i = blockIdx.x * blockDim.x + threadIdx.x;
    if (i < n) { deg[i] = 1; cursor[i] = 0; }
    if (i < 512) bnsum[i] = 0.f;
}

// ---------------- W1/W2 -> bf16 transposed [n][k] --------------------------
__global__ void k_prep(const float* __restrict__ W1, const float* __restrict__ W2,
                       short* __restrict__ Wt1, short* __restrict__ Wt2) {
    int t = blockIdx.x * blockDim.x + threadIdx.x;
    if (t < 128 * 128) {
        int k = t >> 7, nn = t & 127;
        Wt1[nn * 128 + k] = f2bf(W1[t]);
        Wt2[nn * 128 + k] = f2bf(W2[t]);
    }
}

// ---------------- degree histogram over input edges ------------------------
__global__ void k_count(const int* __restrict__ dst, int E, int* __restrict__ deg) {
    int e = blockIdx.x * blockDim.x + threadIdx.x;
    if (e < E) atomicAdd(&deg[dst[e]], 1);
}

// ---------------- exclusive scan (1024-elem chunks) ------------------------
__global__ void k_scan1(const int* __restrict__ deg, int* __restrict__ offs,
                        int* __restrict__ partial, int n) {
    __shared__ int sdata[256];
    int tid = threadIdx.x;
    int base = blockIdx.x * 1024 + tid * 4;
    int v[4]; int s = 0;
    for (int j = 0; j < 4; j++) { int idx = base + j; v[j] = (idx < n) ? deg[idx] : 0; s += v[j]; }
    sdata[tid] = s; __syncthreads();
    for (int d = 1; d < 256; d <<= 1) {
        int t = (tid >= d) ? sdata[tid - d] : 0;
        __syncthreads();
        sdata[tid] += t;
        __syncthreads();
    }
    int excl = sdata[tid] - s;
    if (tid == 255) partial[blockIdx.x] = sdata[255];
    int run = excl;
    for (int j = 0; j < 4; j++) { int idx = base + j; if (idx < n) offs[idx] = run; run += v[j]; }
}

__global__ void k_scan2(int* partial, int nb) {
    __shared__ int sdata[128];
    int t = threadIdx.x;
    int v = (t < nb) ? partial[t] : 0;
    sdata[t] = v; __syncthreads();
    for (int d = 1; d < 128; d <<= 1) {
        int x = (t >= d) ? sdata[t - d] : 0;
        __syncthreads();
        sdata[t] += x;
        __syncthreads();
    }
    if (t < nb) partial[t] = sdata[t] - v;   // exclusive
}

__global__ void k_scan3(int* __restrict__ offs, const int* __restrict__ partial,
                        int n, int total) {
    int i = blockIdx.x * blockDim.x + threadIdx.x;
    if (i < n) offs[i] += partial[i >> 10];
    if (i == 0) offs[n] = total;
}

// ---------------- CSR fill (input edges + self loops) ----------------------
__global__ void k_fill(const int* __restrict__ src, const int* __restrict__ dst,
                       int E, int n, const int* __restrict__ offs,
                       int* __restrict__ cursor, int* __restrict__ csr) {
    int e = blockIdx.x * blockDim.x + threadIdx.x;
    if (e < E) {
        int d = dst[e];
        int p = offs[d] + atomicAdd(&cursor[d], 1);
        csr[p] = src[e];
    } else if (e < E + n) {
        int i = e - E;
        int p = offs[i] + atomicAdd(&cursor[i], 1);
        csr[p] = i;
    }
}

// ---------------- MFMA GEMM: Hb(bf16) = act(X) @ W, alpha fused ------------
// Tile 64 rows x 128 cols, K=128. 4 waves, wave w owns cols [32w,32w+32).
// fuse: act(x)=relu(x*scale[k]+shift[k]).
// Epilogue: alpha_s/d[row] = H[row,:]@av_s/d (fp32, exact from accumulators);
// H transposed through LDS -> coalesced short8 stores.
__global__ __launch_bounds__(256) void k_gemm_mfma(
    const float* __restrict__ X, const short* __restrict__ Wt,
    const float* __restrict__ scale, const float* __restrict__ shift,
    const float* __restrict__ av_s, const float* __restrict__ av_d,
    short* __restrict__ Hb, float* __restrict__ alpha_s, float* __restrict__ alpha_d,
    int n, int fuse)
{
    __shared__ short As[64 * 128];    // 16.4 KB (reused as H transpose buffer)
    __shared__ short Bs[128 * 128];   // 32.8 KB
    __shared__ float part_s[4][64];
    __shared__ float part_d[4][64];
    int t = threadIdx.x;
    int row0 = blockIdx.x * 64;

    // stage B: Wt[n][k] bf16, row-major k-contiguous
    for (int j = 0; j < 8; j++) {
        int idx = j * 256 + t;
        int nn = idx >> 4, cc = idx & 15;
        *(short8*)(Bs + nn * 128 + cc * 8) = *(const short8*)(Wt + nn * 128 + cc * 8);
    }
    // stage A: fp32 -> (BN+relu) -> bf16
    for (int j = 0; j < 8; j++) {
        int idx = j * 256 + t;
        int r = idx >> 5, k4 = idx & 31;
        int gr = row0 + r;
        float4 xv = make_float4(0.f, 0.f, 0.f, 0.f);
        if (gr < n) xv = *(const float4*)(X + (size_t)gr * CDIM + k4 * 4);
        if (fuse) {
            float4 sc = *(const float4*)(scale + k4 * 4);
            float4 sh = *(const float4*)(shift + k4 * 4);
            xv.x = fmaxf(fmaf(xv.x, sc.x, sh.x), 0.f);
            xv.y = fmaxf(fmaf(xv.y, sc.y, sh.y), 0.f);
            xv.z = fmaxf(fmaf(xv.z, sc.z, sh.z), 0.f);
            xv.w = fmaxf(fmaf(xv.w, sc.w, sh.w), 0.f);
        }
        short4v o;
        o.x = f2bf(xv.x); o.y = f2bf(xv.y); o.z = f2bf(xv.z); o.w = f2bf(xv.w);
        *(short4v*)(As + r * 128 + k4 * 4) = o;
    }
    __syncthreads();

    int w = t >> 6, lane = t & 63, q = lane >> 4, c = lane & 15;
    f32x4 zero = {0.f, 0.f, 0.f, 0.f};
    f32x4 acc[4][2];
    for (int i = 0; i < 4; i++) { acc[i][0] = zero; acc[i][1] = zero; }

    for (int ks = 0; ks < 4; ks++) {
        int k0 = ks * 32 + q * 8;
        short8 a0 = *(short8*)(As + (c) * 128 + k0);
        short8 a1 = *(short8*)(As + (16 + c) * 128 + k0);
        short8 a2 = *(short8*)(As + (32 + c) * 128 + k0);
        short8 a3 = *(short8*)(As + (48 + c) * 128 + k0);
        short8 b0 = *(short8*)(Bs + (w * 32 + c) * 128 + k0);
        short8 b1 = *(short8*)(Bs + (w * 32 + 16 + c) * 128 + k0);
        acc[0][0] = __builtin_amdgcn_mfma_f32_16x16x32_bf16(a0, b0, acc[0][0], 0, 0, 0);
        acc[1][0] = __builtin_amdgcn_mfma_f32_16x16x32_bf16(a1, b0, acc[1][0], 0, 0, 0);
        acc[2][0] = __builtin_amdgcn_mfma_f32_16x16x32_bf16(a2, b0, acc[2][0], 0, 0, 0);
        acc[3][0] = __builtin_amdgcn_mfma_f32_16x16x32_bf16(a3, b0, acc[3][0], 0, 0, 0);
        acc[0][1] = __builtin_amdgcn_mfma_f32_16x16x32_bf16(a0, b1, acc[0][1], 0, 0, 0);
        acc[1][1] = __builtin_amdgcn_mfma_f32_16x16x32_bf16(a1, b1, acc[1][1], 0, 0, 0);
        acc[2][1] = __builtin_amdgcn_mfma_f32_16x16x32_bf16(a2, b1, acc[2][1], 0, 0, 0);
        acc[3][1] = __builtin_amdgcn_mfma_f32_16x16x32_bf16(a3, b1, acc[3][1], 0, 0, 0);
    }

    // alpha partial dots: lane's cols are w*32+c and w*32+16+c
    float as0 = av_s[w * 32 + c],      as1 = av_s[w * 32 + 16 + c];
    float ad0 = av_d[w * 32 + c],      ad1 = av_d[w * 32 + 16 + c];
    #pragma unroll
    for (int mt = 0; mt < 4; mt++) {
        #pragma unroll
        for (int r = 0; r < 4; r++) {
            float v0 = acc[mt][0][r], v1 = acc[mt][1][r];
            float ps = v0 * as0 + v1 * as1;
            float pd = v0 * ad0 + v1 * ad1;
            #pragma unroll
            for (int off = 1; off < 16; off <<= 1) {
                ps += __shfl_xor(ps, off);
                pd += __shfl_xor(pd, off);
            }
            if (c == 0) {
                part_s[w][mt * 16 + q * 4 + r] = ps;
                part_d[w][mt * 16 + q * 4 + r] = pd;
            }
        }
    }
    __syncthreads();   // all As reads done, partials visible

    // transpose H (bf16) into As-overlay; D layout: col=c(+16*nt+32w), row=mt*16+q*4+r
    short* Hs = As;
    #pragma unroll
    for (int mt = 0; mt < 4; mt++)
        #pragma unroll
        for (int nt = 0; nt < 2; nt++)
            #pragma unroll
            for (int r = 0; r < 4; r++)
                Hs[(mt * 16 + q * 4 + r) * 128 + w * 32 + nt * 16 + c] = f2bf(acc[mt][nt][r]);

    if (t < 64) {
        int row = row0 + t;
        if (row < n) {
            alpha_s[row] = part_s[0][t] + part_s[1][t] + part_s[2][t] + part_s[3][t];
            alpha_d[row] = part_d[0][t] + part_d[1][t] + part_d[2][t] + part_d[3][t];
        }
    }
    __syncthreads();

    for (int j = 0; j < 4; j++) {
        int idx = j * 256 + t;
        int r = idx >> 4, cc = idx & 15;
        int gr = row0 + r;
        if (gr < n)
            *(short8*)(Hb + (size_t)gr * 128 + cc * 8) = *(short8*)(Hs + r * 128 + cc * 8);
    }
}

// ---------------- per-node softmax + aggregation (one wave per node) -------
// Hb: bf16 features (read as packed uint pairs). Edge weights computed in
// parallel across lanes, broadcast via shuffle for the gather loop.
__global__ __launch_bounds__(256) void k_agg(
    const unsigned* __restrict__ Hb, const int* __restrict__ offs,
    const int* __restrict__ csr, const float* __restrict__ alpha_s,
    const float* __restrict__ alpha_d, const float* __restrict__ bias,
    float* __restrict__ O, int n)
{
    int i = blockIdx.x * 4 + (threadIdx.x >> 6);
    int lane = threadIdx.x & 63;
    if (i >= n) return;
    int o0 = offs[i], o1 = offs[i + 1];
    float adi = alpha_d[i];

    // chunked segment max
    float m = -1e30f;
    for (int c0 = o0; c0 < o1; c0 += 64) {
        int j = c0 + lane;
        float a = (j < o1) ? lrelu(alpha_s[csr[j]] + adi) : -1e30f;
        m = fmaxf(m, a);
    }
    for (int o = 32; o > 0; o >>= 1) m = fmaxf(m, __shfl_xor(m, o));

    // chunked exp-sum
    float se = 0.f;
    for (int c0 = o0; c0 < o1; c0 += 64) {
        int j = c0 + lane;
        if (j < o1) se += __expf(lrelu(alpha_s[csr[j]] + adi) - m);
    }
    for (int o = 32; o > 0; o >>= 1) se += __shfl_xor(se, o);
    float inv = 1.f / se;

    // gather: weights computed one-per-lane, broadcast via shuffle
    float ax = 0.f, ay = 0.f;
    for (int c0 = o0; c0 < o1; c0 += 64) {
        int j = c0 + lane;
        int sj = (j < o1) ? csr[j] : 0;
        float wl = (j < o1) ? __expf(lrelu(alpha_s[sj] + adi) - m) * inv : 0.f;
        int cnt = min(64, o1 - c0);
        for (int b = 0; b < cnt; b++) {
            int s = __shfl(sj, b);
            float wb = __shfl(wl, b);
            unsigned u = Hb[(size_t)s * 64 + lane];
            ax = fmaf(wb, __uint_as_float(u << 16), ax);
            ay = fmaf(wb, __uint_as_float(u & 0xffff0000u), ay);
        }
    }
    float2 b2 = *(const float2*)(bias + lane * 2);
    *(float2*)(O + (size_t)i * CDIM + lane * 2) = make_float2(ax + b2.x, ay + b2.y);
}

// ---------------- BN stats: per-channel sum / sumsq ------------------------
__global__ void k_bnstats(const float* __restrict__ H, int n, float* __restrict__ sums) {
    __shared__ float ls[256], ls2[256];
    int c = threadIdx.x & 127;
    int half = threadIdx.x >> 7;
    float s = 0.f, s2 = 0.f;
    for (int r = blockIdx.x * 2 + half; r < n; r += gridDim.x * 2) {
        float v = H[(size_t)r * CDIM + c];
        s += v; s2 += v * v;
    }
    ls[threadIdx.x] = s; ls2[threadIdx.x] = s2;
    __syncthreads();
    if (threadIdx.x < 128) {
        atomicAdd(&sums[c], ls[threadIdx.x] + ls[threadIdx.x + 128]);
        atomicAdd(&sums[128 + c], ls2[threadIdx.x] + ls2[threadIdx.x + 128]);
    }
}

__global__ void k_bnfin(const float* __restrict__ sums, const float* __restrict__ gamma,
                        const float* __restrict__ beta, float* __restrict__ scale,
                        float* __restrict__ shift, int n) {
    int c = threadIdx.x;   // 128 threads
    float invn = 1.f / (float)n;
    float mean = sums[c] * invn;
    float var = fmaxf(sums[128 + c] * invn - mean * mean, 0.f);
    float sc = gamma[c] * rsqrtf(var + BN_EPS_);
    scale[c] = sc;
    shift[c] = beta[c] - mean * sc;
}

// ---------------- classifier: out = relu(bn(G)) @ Wc + bc ------------------
#define CLS_XS_LD 129
__global__ __launch_bounds__(256) void k_cls(
    const float* __restrict__ G, const float* __restrict__ Wc,
    const float* __restrict__ bc, const float* __restrict__ scale,
    const float* __restrict__ shift, float* __restrict__ out, int n)
{
    __shared__ float Xs[128 * CLS_XS_LD];   // 66.0 KB
    __shared__ float Ws[128 * NCLS_];       // 20.5 KB
    int t = threadIdx.x;
    int row0 = blockIdx.x * 128;

    for (int j = 0; j < 20; j++) Ws[j * 256 + t] = Wc[j * 256 + t];
    for (int j = 0; j < 16; j++) {
        int idx = j * 256 + t;
        int r = idx >> 5, k4 = idx & 31;
        int gr = row0 + r;
        float4 xv = make_float4(0.f, 0.f, 0.f, 0.f);
        if (gr < n) xv = *(const float4*)(G + (size_t)gr * CDIM + k4 * 4);
        float4 sc = *(const float4*)(scale + k4 * 4);
        float4 sh = *(const float4*)(shift + k4 * 4);
        float* xp = Xs + r * CLS_XS_LD + k4 * 4;
        xp[0] = fmaxf(fmaf(xv.x, sc.x, sh.x), 0.f);
        xp[1] = fmaxf(fmaf(xv.y, sc.y, sh.y), 0.f);
        xp[2] = fmaxf(fmaf(xv.z, sc.z, sh.z), 0.f);
        xp[3] = fmaxf(fmaf(xv.w, sc.w, sh.w), 0.f);
    }
    __syncthreads();

    int cg = t & 3;
    int r0 = t >> 2;
    float acc[2][10] = {};
    for (int k = 0; k < CDIM; k++) {
        float x0 = Xs[(r0 * 2 + 0) * CLS_XS_LD + k];
        float x1 = Xs[(r0 * 2 + 1) * CLS_XS_LD + k];
        #pragma unroll
        for (int j = 0; j < 10; j++) {
            float w = Ws[k * NCLS_ + cg * 10 + j];
            acc[0][j] = fmaf(x0, w, acc[0][j]);
            acc[1][j] = fmaf(x1, w, acc[1][j]);
        }
    }
    for (int i = 0; i < 2; i++) {
        int gr = row0 + r0 * 2 + i;
        if (gr < n) {
            #pragma unroll
            for (int j = 0; j < 10; j++)
                out[(size_t)gr * NCLS_ + cg * 10 + j] = acc[i][j] + bc[cg * 10 + j];
        }
    }
}

// ---------------- launch ---------------------------------------------------
extern "C" void kernel_launch(void* const* d_in, const int* in_sizes, int n_in,
                              void* d_out, int out_size, void* d_ws, size_t ws_size,
                              hipStream_t stream)
{
    const float* x   = (const float*)d_in[0];
    const int*   ei  = (const int*)d_in[1];
    const float* W1  = (const float*)d_in[2];
    const float* as1 = (const float*)d_in[3];
    const float* ad1 = (const float*)d_in[4];
    const float* b1  = (const float*)d_in[5];
    const float* g1  = (const float*)d_in[6];
    const float* be1 = (const float*)d_in[7];
    const float* W2  = (const float*)d_in[8];
    const float* as2 = (const float*)d_in[9];
    const float* ad2 = (const float*)d_in[10];
    const float* b2  = (const float*)d_in[11];
    const float* g2  = (const float*)d_in[12];
    const float* be2 = (const float*)d_in[13];
    const float* Wc  = (const float*)d_in[14];
    const float* bc  = (const float*)d_in[15];
    float* out = (float*)d_out;

    int n = in_sizes[0] / CDIM;     // 100000
    int E = in_sizes[1] / 2;        // 1600000
    const int* src = ei;
    const int* dst = ei + E;

    // workspace layout (~86 MB)
    char* p = (char*)d_ws;
    short* Hb      = (short*)p;            p += (size_t)n * CDIM * sizeof(short);
    float* bufB    = (float*)p;            p += (size_t)n * CDIM * sizeof(float);
    float* alpha_s = (float*)p;            p += (size_t)n * sizeof(float);
    float* alpha_d = (float*)p;            p += (size_t)n * sizeof(float);
    float* bnsum   = (float*)p;            p += 512 * sizeof(float);
    float* scale1  = (float*)p;            p += 128 * sizeof(float);
    float* shift1  = (float*)p;            p += 128 * sizeof(float);
    float* scale2  = (float*)p;            p += 128 * sizeof(float);
    float* shift2  = (float*)p;            p += 128 * sizeof(float);
    short* Wt1     = (short*)p;            p += 128 * 128 * sizeof(short);
    short* Wt2     = (short*)p;            p += 128 * 128 * sizeof(short);
    int*   deg     = (int*)p;              p += (size_t)n * sizeof(int);
    int*   cursor  = (int*)p;              p += (size_t)n * sizeof(int);
    int*   offs    = (int*)p;              p += (size_t)(n + 1) * sizeof(int);
    int*   partial = (int*)p;              p += 128 * sizeof(int);
    int*   csr     = (int*)p;

    int nb = (n + 1023) / 1024;

    k_prep<<<dim3(64), dim3(256), 0, stream>>>(W1, W2, Wt1, Wt2);
    k_init<<<dim3((n + 255) / 256), dim3(256), 0, stream>>>(deg, cursor, bnsum, n);
    k_count<<<dim3((E + 255) / 256), dim3(256), 0, stream>>>(dst, E, deg);
    k_scan1<<<dim3(nb), dim3(256), 0, stream>>>(deg, offs, partial, n);
    k_scan2<<<dim3(1), dim3(128), 0, stream>>>(partial, nb);
    k_scan3<<<dim3((n + 255) / 256), dim3(256), 0, stream>>>(offs, partial, n, E + n);
    k_fill<<<dim3((E + n + 255) / 256), dim3(256), 0, stream>>>(src, dst, E, n, offs, cursor, csr);

    dim3 ggrid((n + 63) / 64);
    dim3 wgrid((n + 3) / 4);

    // layer 1
    k_gemm_mfma<<<ggrid, 256, 0, stream>>>(x, Wt1, nullptr, nullptr, as1, ad1,
                                           Hb, alpha_s, alpha_d, n, 0);
    k_agg<<<wgrid, 256, 0, stream>>>((const unsigned*)Hb, offs, csr, alpha_s, alpha_d,
                                     b1, bufB, n);
    k_bnstats<<<dim3(256), dim3(256), 0, stream>>>(bufB, n, bnsum);
    k_bnfin<<<dim3(1), dim3(128), 0, stream>>>(bnsum, g1, be1, scale1, shift1, n);

    // layer 2 (BN1+relu fused into GEMM2 A-staging)
    k_gemm_mfma<<<ggrid, 256, 0, stream>>>(bufB, Wt2, scale1, shift1, as2, ad2,
                                           Hb, alpha_s, alpha_d, n, 1);
    k_agg<<<wgrid, 256, 0, stream>>>((const unsigned*)Hb, offs, csr, alpha_s, alpha_d,
                                     b2, bufB, n);
    k_bnstats<<<dim3(256), dim3(256), 0, stream>>>(bufB, n, bnsum + 256);
    k_bnfin<<<dim3(1), dim3(128), 0, stream>>>(bnsum + 256, g2, be2, scale2, shift2, n);

    // classifier (BN2+relu fused into load)
    k_cls<<<dim3((n + 127) / 128), dim3(256), 0, stream>>>(bufB, Wc, bc, scale2, shift2, out, n);
}

// Round 3
// 658.034 us; speedup vs baseline: 1.3548x; 1.1828x over previous
//
#include <hip/hip_runtime.h>
#include <math.h>

// GAT 2-layer + BN + classifier, MI355X.
// R3: k_agg restructured to ONE pass (online softmax, rescale-on-new-max)
// with a 4-deep pipelined broadcast gather; init+prep merged.

#define CDIM 128
#define NCLS_ 40
#define NEG_SLOPE_ 0.2f
#define BN_EPS_ 1e-5f

using short8  = __attribute__((ext_vector_type(8))) short;
using short4v = __attribute__((ext_vector_type(4))) short;
using f32x4   = __attribute__((ext_vector_type(4))) float;

static __device__ __forceinline__ float lrelu(float a) {
    return a > 0.f ? a : NEG_SLOPE_ * a;
}
// fp32 -> bf16 round-to-nearest-even
static __device__ __forceinline__ short f2bf(float f) {
    unsigned u = __float_as_uint(f);
    u += 0x7fffu + ((u >> 16) & 1u);
    return (short)(u >> 16);
}
static __device__ __forceinline__ float bf_lo(unsigned u) { return __uint_as_float(u << 16); }
static __device__ __forceinline__ float bf_hi(unsigned u) { return __uint_as_float(u & 0xffff0000u); }

// ---------------- setup: deg=1, cursor=0, bn sums zero, W->bf16^T ----------
__global__ void k_setup(int* deg, int* cursor, float* bnsum, int n,
                        const float* __restrict__ W1, const float* __restrict__ W2,
                        short* __restrict__ Wt1, short* __restrict__ Wt2) {
    int i = blockIdx.x * blockDim.x + threadIdx.x;
    if (i < n) { deg[i] = 1; cursor[i] = 0; }
    if (i < 512) bnsum[i] = 0.f;
    if (i < 128 * 128) {
        int k = i >> 7, nn = i & 127;
        Wt1[nn * 128 + k] = f2bf(W1[i]);
        Wt2[nn * 128 + k] = f2bf(W2[i]);
    }
}

// ---------------- degree histogram over input edges ------------------------
__global__ void k_count(const int* __restrict__ dst, int E, int* __restrict__ deg) {
    int e = blockIdx.x * blockDim.x + threadIdx.x;
    if (e < E) atomicAdd(&deg[dst[e]], 1);
}

// ---------------- exclusive scan (1024-elem chunks) ------------------------
__global__ void k_scan1(const int* __restrict__ deg, int* __restrict__ offs,
                        int* __restrict__ partial, int n) {
    __shared__ int sdata[256];
    int tid = threadIdx.x;
    int base = blockIdx.x * 1024 + tid * 4;
    int v[4]; int s = 0;
    for (int j = 0; j < 4; j++) { int idx = base + j; v[j] = (idx < n) ? deg[idx] : 0; s += v[j]; }
    sdata[tid] = s; __syncthreads();
    for (int d = 1; d < 256; d <<= 1) {
        int t = (tid >= d) ? sdata[tid - d] : 0;
        __syncthreads();
        sdata[tid] += t;
        __syncthreads();
    }
    int excl = sdata[tid] - s;
    if (tid == 255) partial[blockIdx.x] = sdata[255];
    int run = excl;
    for (int j = 0; j < 4; j++) { int idx = base + j; if (idx < n) offs[idx] = run; run += v[j]; }
}

__global__ void k_scan2(int* partial, int nb) {
    __shared__ int sdata[128];
    int t = threadIdx.x;
    int v = (t < nb) ? partial[t] : 0;
    sdata[t] = v; __syncthreads();
    for (int d = 1; d < 128; d <<= 1) {
        int x = (t >= d) ? sdata[t - d] : 0;
        __syncthreads();
        sdata[t] += x;
        __syncthreads();
    }
    if (t < nb) partial[t] = sdata[t] - v;   // exclusive
}

__global__ void k_scan3(int* __restrict__ offs, const int* __restrict__ partial,
                        int n, int total) {
    int i = blockIdx.x * blockDim.x + threadIdx.x;
    if (i < n) offs[i] += partial[i >> 10];
    if (i == 0) offs[n] = total;
}

// ---------------- CSR fill (input edges + self loops) ----------------------
__global__ void k_fill(const int* __restrict__ src, const int* __restrict__ dst,
                       int E, int n, const int* __restrict__ offs,
                       int* __restrict__ cursor, int* __restrict__ csr) {
    int e = blockIdx.x * blockDim.x + threadIdx.x;
    if (e < E) {
        int d = dst[e];
        int p = offs[d] + atomicAdd(&cursor[d], 1);
        csr[p] = src[e];
    } else if (e < E + n) {
        int i = e - E;
        int p = offs[i] + atomicAdd(&cursor[i], 1);
        csr[p] = i;
    }
}

// ---------------- MFMA GEMM: Hb(bf16) = act(X) @ W, alpha fused ------------
__global__ __launch_bounds__(256) void k_gemm_mfma(
    const float* __restrict__ X, const short* __restrict__ Wt,
    const float* __restrict__ scale, const float* __restrict__ shift,
    const float* __restrict__ av_s, const float* __restrict__ av_d,
    short* __restrict__ Hb, float* __restrict__ alpha_s, float* __restrict__ alpha_d,
    int n, int fuse)
{
    __shared__ short As[64 * 128];    // 16.4 KB (reused as H transpose buffer)
    __shared__ short Bs[128 * 128];   // 32.8 KB
    __shared__ float part_s[4][64];
    __shared__ float part_d[4][64];
    int t = threadIdx.x;
    int row0 = blockIdx.x * 64;

    for (int j = 0; j < 8; j++) {
        int idx = j * 256 + t;
        int nn = idx >> 4, cc = idx & 15;
        *(short8*)(Bs + nn * 128 + cc * 8) = *(const short8*)(Wt + nn * 128 + cc * 8);
    }
    for (int j = 0; j < 8; j++) {
        int idx = j * 256 + t;
        int r = idx >> 5, k4 = idx & 31;
        int gr = row0 + r;
        float4 xv = make_float4(0.f, 0.f, 0.f, 0.f);
        if (gr < n) xv = *(const float4*)(X + (size_t)gr * CDIM + k4 * 4);
        if (fuse) {
            float4 sc = *(const float4*)(scale + k4 * 4);
            float4 sh = *(const float4*)(shift + k4 * 4);
            xv.x = fmaxf(fmaf(xv.x, sc.x, sh.x), 0.f);
            xv.y = fmaxf(fmaf(xv.y, sc.y, sh.y), 0.f);
            xv.z = fmaxf(fmaf(xv.z, sc.z, sh.z), 0.f);
            xv.w = fmaxf(fmaf(xv.w, sc.w, sh.w), 0.f);
        }
        short4v o;
        o.x = f2bf(xv.x); o.y = f2bf(xv.y); o.z = f2bf(xv.z); o.w = f2bf(xv.w);
        *(short4v*)(As + r * 128 + k4 * 4) = o;
    }
    __syncthreads();

    int w = t >> 6, lane = t & 63, q = lane >> 4, c = lane & 15;
    f32x4 zero = {0.f, 0.f, 0.f, 0.f};
    f32x4 acc[4][2];
    for (int i = 0; i < 4; i++) { acc[i][0] = zero; acc[i][1] = zero; }

    for (int ks = 0; ks < 4; ks++) {
        int k0 = ks * 32 + q * 8;
        short8 a0 = *(short8*)(As + (c) * 128 + k0);
        short8 a1 = *(short8*)(As + (16 + c) * 128 + k0);
        short8 a2 = *(short8*)(As + (32 + c) * 128 + k0);
        short8 a3 = *(short8*)(As + (48 + c) * 128 + k0);
        short8 b0 = *(short8*)(Bs + (w * 32 + c) * 128 + k0);
        short8 b1 = *(short8*)(Bs + (w * 32 + 16 + c) * 128 + k0);
        acc[0][0] = __builtin_amdgcn_mfma_f32_16x16x32_bf16(a0, b0, acc[0][0], 0, 0, 0);
        acc[1][0] = __builtin_amdgcn_mfma_f32_16x16x32_bf16(a1, b0, acc[1][0], 0, 0, 0);
        acc[2][0] = __builtin_amdgcn_mfma_f32_16x16x32_bf16(a2, b0, acc[2][0], 0, 0, 0);
        acc[3][0] = __builtin_amdgcn_mfma_f32_16x16x32_bf16(a3, b0, acc[3][0], 0, 0, 0);
        acc[0][1] = __builtin_amdgcn_mfma_f32_16x16x32_bf16(a0, b1, acc[0][1], 0, 0, 0);
        acc[1][1] = __builtin_amdgcn_mfma_f32_16x16x32_bf16(a1, b1, acc[1][1], 0, 0, 0);
        acc[2][1] = __builtin_amdgcn_mfma_f32_16x16x32_bf16(a2, b1, acc[2][1], 0, 0, 0);
        acc[3][1] = __builtin_amdgcn_mfma_f32_16x16x32_bf16(a3, b1, acc[3][1], 0, 0, 0);
    }

    float as0 = av_s[w * 32 + c],      as1 = av_s[w * 32 + 16 + c];
    float ad0 = av_d[w * 32 + c],      ad1 = av_d[w * 32 + 16 + c];
    #pragma unroll
    for (int mt = 0; mt < 4; mt++) {
        #pragma unroll
        for (int r = 0; r < 4; r++) {
            float v0 = acc[mt][0][r], v1 = acc[mt][1][r];
            float ps = v0 * as0 + v1 * as1;
            float pd = v0 * ad0 + v1 * ad1;
            #pragma unroll
            for (int off = 1; off < 16; off <<= 1) {
                ps += __shfl_xor(ps, off);
                pd += __shfl_xor(pd, off);
            }
            if (c == 0) {
                part_s[w][mt * 16 + q * 4 + r] = ps;
                part_d[w][mt * 16 + q * 4 + r] = pd;
            }
        }
    }
    __syncthreads();

    short* Hs = As;
    #pragma unroll
    for (int mt = 0; mt < 4; mt++)
        #pragma unroll
        for (int nt = 0; nt < 2; nt++)
            #pragma unroll
            for (int r = 0; r < 4; r++)
                Hs[(mt * 16 + q * 4 + r) * 128 + w * 32 + nt * 16 + c] = f2bf(acc[mt][nt][r]);

    if (t < 64) {
        int row = row0 + t;
        if (row < n) {
            alpha_s[row] = part_s[0][t] + part_s[1][t] + part_s[2][t] + part_s[3][t];
            alpha_d[row] = part_d[0][t] + part_d[1][t] + part_d[2][t] + part_d[3][t];
        }
    }
    __syncthreads();

    for (int j = 0; j < 4; j++) {
        int idx = j * 256 + t;
        int r = idx >> 4, cc = idx & 15;
        int gr = row0 + r;
        if (gr < n)
            *(short8*)(Hb + (size_t)gr * 128 + cc * 8) = *(short8*)(Hs + r * 128 + cc * 8);
    }
}

// ---------------- ONE-PASS softmax + aggregation (one wave per node) -------
// Online softmax: running max m with rescale of (se, ax, ay) on new max.
// Weights computed lane-parallel per 64-edge chunk, broadcast via shuffle;
// feature gather pipelined 4 deep (independent loads in flight).
__global__ __launch_bounds__(256) void k_agg(
    const unsigned* __restrict__ Hb, const int* __restrict__ offs,
    const int* __restrict__ csr, const float* __restrict__ alpha_s,
    const float* __restrict__ alpha_d, const float* __restrict__ bias,
    float* __restrict__ O, int n)
{
    int i = blockIdx.x * 4 + (threadIdx.x >> 6);
    int lane = threadIdx.x & 63;
    if (i >= n) return;
    int o0 = offs[i], o1 = offs[i + 1];
    float adi = alpha_d[i];

    float m = -1e30f;            // running max
    float se = 0.f;              // per-lane partial of sum(exp(a-m))
    float ax = 0.f, ay = 0.f;    // per-lane accumulators (2 channels)

    for (int c0 = o0; c0 < o1; c0 += 64) {
        int j = c0 + lane;
        int cnt = min(64, o1 - c0);
        int sj = (j < o1) ? csr[j] : 0;
        float a = (j < o1) ? lrelu(alpha_s[sj] + adi) : -1e30f;

        float cm = a;
        #pragma unroll
        for (int o = 32; o > 0; o >>= 1) cm = fmaxf(cm, __shfl_xor(cm, o));
        if (cm > m) {
            float r = __expf(m - cm);
            se *= r; ax *= r; ay *= r;
            m = cm;
        }
        float wl = (j < o1) ? __expf(a - m) : 0.f;
        se += wl;

        int b = 0;
        for (; b + 4 <= cnt; b += 4) {
            int   s0 = __shfl(sj, b),     s1 = __shfl(sj, b + 1);
            int   s2 = __shfl(sj, b + 2), s3 = __shfl(sj, b + 3);
            float w0 = __shfl(wl, b),     w1 = __shfl(wl, b + 1);
            float w2 = __shfl(wl, b + 2), w3 = __shfl(wl, b + 3);
            unsigned u0 = Hb[(size_t)s0 * 64 + lane];
            unsigned u1 = Hb[(size_t)s1 * 64 + lane];
            unsigned u2 = Hb[(size_t)s2 * 64 + lane];
            unsigned u3 = Hb[(size_t)s3 * 64 + lane];
            ax = fmaf(w0, bf_lo(u0), ax); ay = fmaf(w0, bf_hi(u0), ay);
            ax = fmaf(w1, bf_lo(u1), ax); ay = fmaf(w1, bf_hi(u1), ay);
            ax = fmaf(w2, bf_lo(u2), ax); ay = fmaf(w2, bf_hi(u2), ay);
            ax = fmaf(w3, bf_lo(u3), ax); ay = fmaf(w3, bf_hi(u3), ay);
        }
        for (; b < cnt; b++) {
            int   s = __shfl(sj, b);
            float w = __shfl(wl, b);
            unsigned u = Hb[(size_t)s * 64 + lane];
            ax = fmaf(w, bf_lo(u), ax); ay = fmaf(w, bf_hi(u), ay);
        }
    }

    #pragma unroll
    for (int o = 32; o > 0; o >>= 1) se += __shfl_xor(se, o);
    float inv = 1.f / se;
    float2 b2 = *(const float2*)(bias + lane * 2);
    *(float2*)(O + (size_t)i * CDIM + lane * 2) =
        make_float2(fmaf(ax, inv, b2.x), fmaf(ay, inv, b2.y));
}

// ---------------- BN stats: per-channel sum / sumsq ------------------------
__global__ void k_bnstats(const float* __restrict__ H, int n, float* __restrict__ sums) {
    __shared__ float ls[256], ls2[256];
    int c = threadIdx.x & 127;
    int half = threadIdx.x >> 7;
    float s = 0.f, s2 = 0.f;
    for (int r = blockIdx.x * 2 + half; r < n; r += gridDim.x * 2) {
        float v = H[(size_t)r * CDIM + c];
        s += v; s2 += v * v;
    }
    ls[threadIdx.x] = s; ls2[threadIdx.x] = s2;
    __syncthreads();
    if (threadIdx.x < 128) {
        atomicAdd(&sums[c], ls[threadIdx.x] + ls[threadIdx.x + 128]);
        atomicAdd(&sums[128 + c], ls2[threadIdx.x] + ls2[threadIdx.x + 128]);
    }
}

__global__ void k_bnfin(const float* __restrict__ sums, const float* __restrict__ gamma,
                        const float* __restrict__ beta, float* __restrict__ scale,
                        float* __restrict__ shift, int n) {
    int c = threadIdx.x;   // 128 threads
    float invn = 1.f / (float)n;
    float mean = sums[c] * invn;
    float var = fmaxf(sums[128 + c] * invn - mean * mean, 0.f);
    float sc = gamma[c] * rsqrtf(var + BN_EPS_);
    scale[c] = sc;
    shift[c] = beta[c] - mean * sc;
}

// ---------------- classifier: out = relu(bn(G)) @ Wc + bc ------------------
#define CLS_XS_LD 129
__global__ __launch_bounds__(256) void k_cls(
    const float* __restrict__ G, const float* __restrict__ Wc,
    const float* __restrict__ bc, const float* __restrict__ scale,
    const float* __restrict__ shift, float* __restrict__ out, int n)
{
    __shared__ float Xs[128 * CLS_XS_LD];   // 66.0 KB
    __shared__ float Ws[128 * NCLS_];       // 20.5 KB
    int t = threadIdx.x;
    int row0 = blockIdx.x * 128;

    for (int j = 0; j < 20; j++) Ws[j * 256 + t] = Wc[j * 256 + t];
    for (int j = 0; j < 16; j++) {
        int idx = j * 256 + t;
        int r = idx >> 5, k4 = idx & 31;
        int gr = row0 + r;
        float4 xv = make_float4(0.f, 0.f, 0.f, 0.f);
        if (gr < n) xv = *(const float4*)(G + (size_t)gr * CDIM + k4 * 4);
        float4 sc = *(const float4*)(scale + k4 * 4);
        float4 sh = *(const float4*)(shift + k4 * 4);
        float* xp = Xs + r * CLS_XS_LD + k4 * 4;
        xp[0] = fmaxf(fmaf(xv.x, sc.x, sh.x), 0.f);
        xp[1] = fmaxf(fmaf(xv.y, sc.y, sh.y), 0.f);
        xp[2] = fmaxf(fmaf(xv.z, sc.z, sh.z), 0.f);
        xp[3] = fmaxf(fmaf(xv.w, sc.w, sh.w), 0.f);
    }
    __syncthreads();

    int cg = t & 3;
    int r0 = t >> 2;
    float acc[2][10] = {};
    for (int k = 0; k < CDIM; k++) {
        float x0 = Xs[(r0 * 2 + 0) * CLS_XS_LD + k];
        float x1 = Xs[(r0 * 2 + 1) * CLS_XS_LD + k];
        #pragma unroll
        for (int j = 0; j < 10; j++) {
            float w = Ws[k * NCLS_ + cg * 10 + j];
            acc[0][j] = fmaf(x0, w, acc[0][j]);
            acc[1][j] = fmaf(x1, w, acc[1][j]);
        }
    }
    for (int i = 0; i < 2; i++) {
        int gr = row0 + r0 * 2 + i;
        if (gr < n) {
            #pragma unroll
            for (int j = 0; j < 10; j++)
                out[(size_t)gr * NCLS_ + cg * 10 + j] = acc[i][j] + bc[cg * 10 + j];
        }
    }
}

// ---------------- launch ---------------------------------------------------
extern "C" void kernel_launch(void* const* d_in, const int* in_sizes, int n_in,
                              void* d_out, int out_size, void* d_ws, size_t ws_size,
                              hipStream_t stream)
{
    const float* x   = (const float*)d_in[0];
    const int*   ei  = (const int*)d_in[1];
    const float* W1  = (const float*)d_in[2];
    const float* as1 = (const float*)d_in[3];
    const float* ad1 = (const float*)d_in[4];
    const float* b1  = (const float*)d_in[5];
    const float* g1  = (const float*)d_in[6];
    const float* be1 = (const float*)d_in[7];
    const float* W2  = (const float*)d_in[8];
    const float* as2 = (const float*)d_in[9];
    const float* ad2 = (const float*)d_in[10];
    const float* b2  = (const float*)d_in[11];
    const float* g2  = (const float*)d_in[12];
    const float* be2 = (const float*)d_in[13];
    const float* Wc  = (const float*)d_in[14];
    const float* bc  = (const float*)d_in[15];
    float* out = (float*)d_out;

    int n = in_sizes[0] / CDIM;     // 100000
    int E = in_sizes[1] / 2;        // 1600000
    const int* src = ei;
    const int* dst = ei + E;

    // workspace layout
    char* p = (char*)d_ws;
    short* Hb      = (short*)p;            p += (size_t)n * CDIM * sizeof(short);
    float* bufB    = (float*)p;            p += (size_t)n * CDIM * sizeof(float);
    float* alpha_s = (float*)p;            p += (size_t)n * sizeof(float);
    float* alpha_d = (float*)p;            p += (size_t)n * sizeof(float);
    float* bnsum   = (float*)p;            p += 512 * sizeof(float);
    float* scale1  = (float*)p;            p += 128 * sizeof(float);
    float* shift1  = (float*)p;            p += 128 * sizeof(float);
    float* scale2  = (float*)p;            p += 128 * sizeof(float);
    float* shift2  = (float*)p;            p += 128 * sizeof(float);
    short* Wt1     = (short*)p;            p += 128 * 128 * sizeof(short);
    short* Wt2     = (short*)p;            p += 128 * 128 * sizeof(short);
    int*   deg     = (int*)p;              p += (size_t)n * sizeof(int);
    int*   cursor  = (int*)p;              p += (size_t)n * sizeof(int);
    int*   offs    = (int*)p;              p += (size_t)(n + 1) * sizeof(int);
    int*   partial = (int*)p;              p += 128 * sizeof(int);
    int*   csr     = (int*)p;

    int nb = (n + 1023) / 1024;

    k_setup<<<dim3((n + 255) / 256), dim3(256), 0, stream>>>(deg, cursor, bnsum, n,
                                                             W1, W2, Wt1, Wt2);
    k_count<<<dim3((E + 255) / 256), dim3(256), 0, stream>>>(dst, E, deg);
    k_scan1<<<dim3(nb), dim3(256), 0, stream>>>(deg, offs, partial, n);
    k_scan2<<<dim3(1), dim3(128), 0, stream>>>(partial, nb);
    k_scan3<<<dim3((n + 255) / 256), dim3(256), 0, stream>>>(offs, partial, n, E + n);
    k_fill<<<dim3((E + n + 255) / 256), dim3(256), 0, stream>>>(src, dst, E, n, offs, cursor, csr);

    dim3 ggrid((n + 63) / 64);
    dim3 wgrid((n + 3) / 4);

    // layer 1
    k_gemm_mfma<<<ggrid, 256, 0, stream>>>(x, Wt1, nullptr, nullptr, as1, ad1,
                                           Hb, alpha_s, alpha_d, n, 0);
    k_agg<<<wgrid, 256, 0, stream>>>((const unsigned*)Hb, offs, csr, alpha_s, alpha_d,
                                     b1, bufB, n);
    k_bnstats<<<dim3(256), dim3(256), 0, stream>>>(bufB, n, bnsum);
    k_bnfin<<<dim3(1), dim3(128), 0, stream>>>(bnsum, g1, be1, scale1, shift1, n);

    // layer 2 (BN1+relu fused into GEMM2 A-staging)
    k_gemm_mfma<<<ggrid, 256, 0, stream>>>(bufB, Wt2, scale1, shift1, as2, ad2,
                                           Hb, alpha_s, alpha_d, n, 1);
    k_agg<<<wgrid, 256, 0, stream>>>((const unsigned*)Hb, offs, csr, alpha_s, alpha_d,
                                     b2, bufB, n);
    k_bnstats<<<dim3(256), dim3(256), 0, stream>>>(bufB, n, bnsum + 256);
    k_bnfin<<<dim3(1), dim3(128), 0, stream>>>(bnsum + 256, g2, be2, scale2, shift2, n);

    // classifier (BN2+relu fused into load)
    k_cls<<<dim3((n + 127) / 128), dim3(256), 0, stream>>>(bufB, Wc, bc, scale2, shift2, out, n);
}

// Round 4
// 590.321 us; speedup vs baseline: 1.5102x; 1.1147x over previous
//
#include <hip/hip_runtime.h>
#include <math.h>

// GAT 2-layer + BN + classifier, MI355X.
// R4: atomic-free CSR fill (rel captured in count), scan3+self-loops merged
// into fill, BN finalize folded into GEMM/cls staging, 8-deep predicated
// gather in k_agg. 12 launches.

#define CDIM 128
#define NCLS_ 40
#define NEG_SLOPE_ 0.2f
#define BN_EPS_ 1e-5f

using short8  = __attribute__((ext_vector_type(8))) short;
using short4v = __attribute__((ext_vector_type(4))) short;
using f32x4   = __attribute__((ext_vector_type(4))) float;

static __device__ __forceinline__ float lrelu(float a) {
    return a > 0.f ? a : NEG_SLOPE_ * a;
}
// fp32 -> bf16 round-to-nearest-even
static __device__ __forceinline__ short f2bf(float f) {
    unsigned u = __float_as_uint(f);
    u += 0x7fffu + ((u >> 16) & 1u);
    return (short)(u >> 16);
}
static __device__ __forceinline__ float bf_lo(unsigned u) { return __uint_as_float(u << 16); }
static __device__ __forceinline__ float bf_hi(unsigned u) { return __uint_as_float(u & 0xffff0000u); }

// ---------------- setup: deg=1 (self-loop slot 0), bn sums 0, W->bf16^T ----
__global__ void k_setup(int* deg, float* bnsum, int n,
                        const float* __restrict__ W1, const float* __restrict__ W2,
                        short* __restrict__ Wt1, short* __restrict__ Wt2) {
    int i = blockIdx.x * blockDim.x + threadIdx.x;
    if (i < n) deg[i] = 1;
    if (i < 512) bnsum[i] = 0.f;
    if (i < 128 * 128) {
        int k = i >> 7, nn = i & 127;
        Wt1[nn * 128 + k] = f2bf(W1[i]);
        Wt2[nn * 128 + k] = f2bf(W2[i]);
    }
}

// ---------------- degree histogram; rel[e] = slot within dst's segment -----
__global__ void k_count(const int* __restrict__ dst, int E,
                        int* __restrict__ deg, int* __restrict__ rel) {
    int e = blockIdx.x * blockDim.x + threadIdx.x;
    if (e < E) rel[e] = atomicAdd(&deg[dst[e]], 1);
}

// ---------------- exclusive scan (1024-elem chunks) ------------------------
__global__ void k_scan1(const int* __restrict__ deg, int* __restrict__ offs,
                        int* __restrict__ partial, int n) {
    __shared__ int sdata[256];
    int tid = threadIdx.x;
    int base = blockIdx.x * 1024 + tid * 4;
    int v[4]; int s = 0;
    for (int j = 0; j < 4; j++) { int idx = base + j; v[j] = (idx < n) ? deg[idx] : 0; s += v[j]; }
    sdata[tid] = s; __syncthreads();
    for (int d = 1; d < 256; d <<= 1) {
        int t = (tid >= d) ? sdata[tid - d] : 0;
        __syncthreads();
        sdata[tid] += t;
        __syncthreads();
    }
    int excl = sdata[tid] - s;
    if (tid == 255) partial[blockIdx.x] = sdata[255];
    int run = excl;
    for (int j = 0; j < 4; j++) { int idx = base + j; if (idx < n) offs[idx] = run; run += v[j]; }
}

__global__ void k_scan2(int* partial, int nb) {
    __shared__ int sdata[128];
    int t = threadIdx.x;
    int v = (t < nb) ? partial[t] : 0;
    sdata[t] = v; __syncthreads();
    for (int d = 1; d < 128; d <<= 1) {
        int x = (t >= d) ? sdata[t - d] : 0;
        __syncthreads();
        sdata[t] += x;
        __syncthreads();
    }
    if (t < nb) partial[t] = sdata[t] - v;   // exclusive
}

// ---------------- fill: edges (no atomic) + self loops + final offs --------
__global__ void k_fill(const int* __restrict__ src, const int* __restrict__ dst,
                       const int* __restrict__ rel, int E, int n,
                       const int* __restrict__ offs_raw, const int* __restrict__ partial,
                       int* __restrict__ offs_fin, int* __restrict__ csr) {
    int t = blockIdx.x * blockDim.x + threadIdx.x;
    if (t < E) {
        int d = dst[t];
        int p = offs_raw[d] + partial[d >> 10] + rel[t];
        csr[p] = src[t];
    } else if (t < E + n) {
        int i = t - E;
        int base = offs_raw[i] + partial[i >> 10];
        offs_fin[i] = base;
        csr[base] = i;                  // self-loop occupies slot 0
        if (i == 0) offs_fin[n] = E + n;
    }
}

// ---------------- MFMA GEMM: Hb(bf16) = act(X) @ W, alpha fused ------------
// fuse: act(x)=relu(x*scale+shift), scale/shift computed from raw BN sums.
__global__ __launch_bounds__(256) void k_gemm_mfma(
    const float* __restrict__ X, const short* __restrict__ Wt,
    const float* __restrict__ bnsum, const float* __restrict__ gamma,
    const float* __restrict__ beta, float invn,
    const float* __restrict__ av_s, const float* __restrict__ av_d,
    short* __restrict__ Hb, float* __restrict__ alpha_s, float* __restrict__ alpha_d,
    int n, int fuse)
{
    __shared__ short As[64 * 128];    // 16.4 KB (reused as H transpose buffer)
    __shared__ short Bs[128 * 128];   // 32.8 KB
    __shared__ float part_s[4][64];
    __shared__ float part_d[4][64];
    int t = threadIdx.x;
    int row0 = blockIdx.x * 64;

    for (int j = 0; j < 8; j++) {
        int idx = j * 256 + t;
        int nn = idx >> 4, cc = idx & 15;
        *(short8*)(Bs + nn * 128 + cc * 8) = *(const short8*)(Wt + nn * 128 + cc * 8);
    }
    // per-thread BN scale/shift for its 4 channels (constant across j)
    float4 sc4 = make_float4(1.f, 1.f, 1.f, 1.f);
    float4 sh4 = make_float4(0.f, 0.f, 0.f, 0.f);
    if (fuse) {
        int cb = (t & 31) * 4;
        float4 s0 = *(const float4*)(bnsum + cb);
        float4 s1 = *(const float4*)(bnsum + 128 + cb);
        float4 gm = *(const float4*)(gamma + cb);
        float4 bt = *(const float4*)(beta + cb);
        float mean, var;
        mean = s0.x * invn; var = fmaxf(s1.x * invn - mean * mean, 0.f);
        sc4.x = gm.x * rsqrtf(var + BN_EPS_); sh4.x = bt.x - mean * sc4.x;
        mean = s0.y * invn; var = fmaxf(s1.y * invn - mean * mean, 0.f);
        sc4.y = gm.y * rsqrtf(var + BN_EPS_); sh4.y = bt.y - mean * sc4.y;
        mean = s0.z * invn; var = fmaxf(s1.z * invn - mean * mean, 0.f);
        sc4.z = gm.z * rsqrtf(var + BN_EPS_); sh4.z = bt.z - mean * sc4.z;
        mean = s0.w * invn; var = fmaxf(s1.w * invn - mean * mean, 0.f);
        sc4.w = gm.w * rsqrtf(var + BN_EPS_); sh4.w = bt.w - mean * sc4.w;
    }
    for (int j = 0; j < 8; j++) {
        int idx = j * 256 + t;
        int r = idx >> 5, k4 = idx & 31;
        int gr = row0 + r;
        float4 xv = make_float4(0.f, 0.f, 0.f, 0.f);
        if (gr < n) xv = *(const float4*)(X + (size_t)gr * CDIM + k4 * 4);
        if (fuse) {
            xv.x = fmaxf(fmaf(xv.x, sc4.x, sh4.x), 0.f);
            xv.y = fmaxf(fmaf(xv.y, sc4.y, sh4.y), 0.f);
            xv.z = fmaxf(fmaf(xv.z, sc4.z, sh4.z), 0.f);
            xv.w = fmaxf(fmaf(xv.w, sc4.w, sh4.w), 0.f);
        }
        short4v o;
        o.x = f2bf(xv.x); o.y = f2bf(xv.y); o.z = f2bf(xv.z); o.w = f2bf(xv.w);
        *(short4v*)(As + r * 128 + k4 * 4) = o;
    }
    __syncthreads();

    int w = t >> 6, lane = t & 63, q = lane >> 4, c = lane & 15;
    f32x4 zero = {0.f, 0.f, 0.f, 0.f};
    f32x4 acc[4][2];
    for (int i = 0; i < 4; i++) { acc[i][0] = zero; acc[i][1] = zero; }

    for (int ks = 0; ks < 4; ks++) {
        int k0 = ks * 32 + q * 8;
        short8 a0 = *(short8*)(As + (c) * 128 + k0);
        short8 a1 = *(short8*)(As + (16 + c) * 128 + k0);
        short8 a2 = *(short8*)(As + (32 + c) * 128 + k0);
        short8 a3 = *(short8*)(As + (48 + c) * 128 + k0);
        short8 b0 = *(short8*)(Bs + (w * 32 + c) * 128 + k0);
        short8 b1 = *(short8*)(Bs + (w * 32 + 16 + c) * 128 + k0);
        acc[0][0] = __builtin_amdgcn_mfma_f32_16x16x32_bf16(a0, b0, acc[0][0], 0, 0, 0);
        acc[1][0] = __builtin_amdgcn_mfma_f32_16x16x32_bf16(a1, b0, acc[1][0], 0, 0, 0);
        acc[2][0] = __builtin_amdgcn_mfma_f32_16x16x32_bf16(a2, b0, acc[2][0], 0, 0, 0);
        acc[3][0] = __builtin_amdgcn_mfma_f32_16x16x32_bf16(a3, b0, acc[3][0], 0, 0, 0);
        acc[0][1] = __builtin_amdgcn_mfma_f32_16x16x32_bf16(a0, b1, acc[0][1], 0, 0, 0);
        acc[1][1] = __builtin_amdgcn_mfma_f32_16x16x32_bf16(a1, b1, acc[1][1], 0, 0, 0);
        acc[2][1] = __builtin_amdgcn_mfma_f32_16x16x32_bf16(a2, b1, acc[2][1], 0, 0, 0);
        acc[3][1] = __builtin_amdgcn_mfma_f32_16x16x32_bf16(a3, b1, acc[3][1], 0, 0, 0);
    }

    float as0 = av_s[w * 32 + c],      as1 = av_s[w * 32 + 16 + c];
    float ad0 = av_d[w * 32 + c],      ad1 = av_d[w * 32 + 16 + c];
    #pragma unroll
    for (int mt = 0; mt < 4; mt++) {
        #pragma unroll
        for (int r = 0; r < 4; r++) {
            float v0 = acc[mt][0][r], v1 = acc[mt][1][r];
            float ps = v0 * as0 + v1 * as1;
            float pd = v0 * ad0 + v1 * ad1;
            #pragma unroll
            for (int off = 1; off < 16; off <<= 1) {
                ps += __shfl_xor(ps, off);
                pd += __shfl_xor(pd, off);
            }
            if (c == 0) {
                part_s[w][mt * 16 + q * 4 + r] = ps;
                part_d[w][mt * 16 + q * 4 + r] = pd;
            }
        }
    }
    __syncthreads();

    short* Hs = As;
    #pragma unroll
    for (int mt = 0; mt < 4; mt++)
        #pragma unroll
        for (int nt = 0; nt < 2; nt++)
            #pragma unroll
            for (int r = 0; r < 4; r++)
                Hs[(mt * 16 + q * 4 + r) * 128 + w * 32 + nt * 16 + c] = f2bf(acc[mt][nt][r]);

    if (t < 64) {
        int row = row0 + t;
        if (row < n) {
            alpha_s[row] = part_s[0][t] + part_s[1][t] + part_s[2][t] + part_s[3][t];
            alpha_d[row] = part_d[0][t] + part_d[1][t] + part_d[2][t] + part_d[3][t];
        }
    }
    __syncthreads();

    for (int j = 0; j < 4; j++) {
        int idx = j * 256 + t;
        int r = idx >> 4, cc = idx & 15;
        int gr = row0 + r;
        if (gr < n)
            *(short8*)(Hb + (size_t)gr * 128 + cc * 8) = *(short8*)(Hs + r * 128 + cc * 8);
    }
}

// ---------------- ONE-PASS softmax + aggregation (one wave per node) -------
__global__ __launch_bounds__(256) void k_agg(
    const unsigned* __restrict__ Hb, const int* __restrict__ offs,
    const int* __restrict__ csr, const float* __restrict__ alpha_s,
    const float* __restrict__ alpha_d, const float* __restrict__ bias,
    float* __restrict__ O, int n)
{
    int i = blockIdx.x * 4 + (threadIdx.x >> 6);
    int lane = threadIdx.x & 63;
    if (i >= n) return;
    int o0 = offs[i], o1 = offs[i + 1];
    float adi = alpha_d[i];

    float m = -1e30f;
    float se = 0.f;
    float ax = 0.f, ay = 0.f;

    for (int c0 = o0; c0 < o1; c0 += 64) {
        int j = c0 + lane;
        int cnt = min(64, o1 - c0);
        int sj = (j < o1) ? csr[j] : 0;
        float a = (j < o1) ? lrelu(alpha_s[sj] + adi) : -1e30f;

        float cm = a;
        #pragma unroll
        for (int o = 32; o > 0; o >>= 1) cm = fmaxf(cm, __shfl_xor(cm, o));
        if (cm > m) {
            float r = __expf(m - cm);
            se *= r; ax *= r; ay *= r;
            m = cm;
        }
        float wl = (j < o1) ? __expf(a - m) : 0.f;
        se += wl;

        // 8-deep predicated broadcast gather (no serial tail)
        for (int b = 0; b < cnt; b += 8) {
            unsigned u[8]; float wv[8];
            #pragma unroll
            for (int q2 = 0; q2 < 8; q2++) {
                int e = b + q2;
                int el = (e < cnt) ? e : (cnt - 1);
                int s = __shfl(sj, el);
                wv[q2] = (e < cnt) ? __shfl(wl, el) : 0.f;
                u[q2] = Hb[(size_t)s * 64 + lane];
            }
            #pragma unroll
            for (int q2 = 0; q2 < 8; q2++) {
                ax = fmaf(wv[q2], bf_lo(u[q2]), ax);
                ay = fmaf(wv[q2], bf_hi(u[q2]), ay);
            }
        }
    }

    #pragma unroll
    for (int o = 32; o > 0; o >>= 1) se += __shfl_xor(se, o);
    float inv = 1.f / se;
    float2 b2 = *(const float2*)(bias + lane * 2);
    *(float2*)(O + (size_t)i * CDIM + lane * 2) =
        make_float2(fmaf(ax, inv, b2.x), fmaf(ay, inv, b2.y));
}

// ---------------- BN stats: per-channel sum / sumsq ------------------------
__global__ void k_bnstats(const float* __restrict__ H, int n, float* __restrict__ sums) {
    __shared__ float ls[256], ls2[256];
    int c = threadIdx.x & 127;
    int half = threadIdx.x >> 7;
    float s = 0.f, s2 = 0.f;
    for (int r = blockIdx.x * 2 + half; r < n; r += gridDim.x * 2) {
        float v = H[(size_t)r * CDIM + c];
        s += v; s2 += v * v;
    }
    ls[threadIdx.x] = s; ls2[threadIdx.x] = s2;
    __syncthreads();
    if (threadIdx.x < 128) {
        atomicAdd(&sums[c], ls[threadIdx.x] + ls[threadIdx.x + 128]);
        atomicAdd(&sums[128 + c], ls2[threadIdx.x] + ls2[threadIdx.x + 128]);
    }
}

// ---------------- classifier: out = relu(bn(G)) @ Wc + bc ------------------
#define CLS_XS_LD 129
__global__ __launch_bounds__(256) void k_cls(
    const float* __restrict__ G, const float* __restrict__ Wc,
    const float* __restrict__ bc, const float* __restrict__ bnsum,
    const float* __restrict__ gamma, const float* __restrict__ beta, float invn,
    float* __restrict__ out, int n)
{
    __shared__ float Xs[128 * CLS_XS_LD];   // 66.0 KB
    __shared__ float Ws[128 * NCLS_];       // 20.5 KB
    int t = threadIdx.x;
    int row0 = blockIdx.x * 128;

    for (int j = 0; j < 20; j++) Ws[j * 256 + t] = Wc[j * 256 + t];

    float4 sc4, sh4;
    {
        int cb = (t & 31) * 4;
        float4 s0 = *(const float4*)(bnsum + cb);
        float4 s1 = *(const float4*)(bnsum + 128 + cb);
        float4 gm = *(const float4*)(gamma + cb);
        float4 bt = *(const float4*)(beta + cb);
        float mean, var;
        mean = s0.x * invn; var = fmaxf(s1.x * invn - mean * mean, 0.f);
        sc4.x = gm.x * rsqrtf(var + BN_EPS_); sh4.x = bt.x - mean * sc4.x;
        mean = s0.y * invn; var = fmaxf(s1.y * invn - mean * mean, 0.f);
        sc4.y = gm.y * rsqrtf(var + BN_EPS_); sh4.y = bt.y - mean * sc4.y;
        mean = s0.z * invn; var = fmaxf(s1.z * invn - mean * mean, 0.f);
        sc4.z = gm.z * rsqrtf(var + BN_EPS_); sh4.z = bt.z - mean * sc4.z;
        mean = s0.w * invn; var = fmaxf(s1.w * invn - mean * mean, 0.f);
        sc4.w = gm.w * rsqrtf(var + BN_EPS_); sh4.w = bt.w - mean * sc4.w;
    }
    for (int j = 0; j < 16; j++) {
        int idx = j * 256 + t;
        int r = idx >> 5, k4 = idx & 31;
        int gr = row0 + r;
        float4 xv = make_float4(0.f, 0.f, 0.f, 0.f);
        if (gr < n) xv = *(const float4*)(G + (size_t)gr * CDIM + k4 * 4);
        float* xp = Xs + r * CLS_XS_LD + k4 * 4;
        xp[0] = fmaxf(fmaf(xv.x, sc4.x, sh4.x), 0.f);
        xp[1] = fmaxf(fmaf(xv.y, sc4.y, sh4.y), 0.f);
        xp[2] = fmaxf(fmaf(xv.z, sc4.z, sh4.z), 0.f);
        xp[3] = fmaxf(fmaf(xv.w, sc4.w, sh4.w), 0.f);
    }
    __syncthreads();

    int cg = t & 3;
    int r0 = t >> 2;
    float acc[2][10] = {};
    for (int k = 0; k < CDIM; k++) {
        float x0 = Xs[(r0 * 2 + 0) * CLS_XS_LD + k];
        float x1 = Xs[(r0 * 2 + 1) * CLS_XS_LD + k];
        #pragma unroll
        for (int j = 0; j < 10; j++) {
            float w = Ws[k * NCLS_ + cg * 10 + j];
            acc[0][j] = fmaf(x0, w, acc[0][j]);
            acc[1][j] = fmaf(x1, w, acc[1][j]);
        }
    }
    for (int i = 0; i < 2; i++) {
        int gr = row0 + r0 * 2 + i;
        if (gr < n) {
            #pragma unroll
            for (int j = 0; j < 10; j++)
                out[(size_t)gr * NCLS_ + cg * 10 + j] = acc[i][j] + bc[cg * 10 + j];
        }
    }
}

// ---------------- launch ---------------------------------------------------
extern "C" void kernel_launch(void* const* d_in, const int* in_sizes, int n_in,
                              void* d_out, int out_size, void* d_ws, size_t ws_size,
                              hipStream_t stream)
{
    const float* x   = (const float*)d_in[0];
    const int*   ei  = (const int*)d_in[1];
    const float* W1  = (const float*)d_in[2];
    const float* as1 = (const float*)d_in[3];
    const float* ad1 = (const float*)d_in[4];
    const float* b1  = (const float*)d_in[5];
    const float* g1  = (const float*)d_in[6];
    const float* be1 = (const float*)d_in[7];
    const float* W2  = (const float*)d_in[8];
    const float* as2 = (const float*)d_in[9];
    const float* ad2 = (const float*)d_in[10];
    const float* b2  = (const float*)d_in[11];
    const float* g2  = (const float*)d_in[12];
    const float* be2 = (const float*)d_in[13];
    const float* Wc  = (const float*)d_in[14];
    const float* bc  = (const float*)d_in[15];
    float* out = (float*)d_out;

    int n = in_sizes[0] / CDIM;     // 100000
    int E = in_sizes[1] / 2;        // 1600000
    const int* src = ei;
    const int* dst = ei + E;
    float invn = 1.f / (float)n;

    // workspace layout
    char* p = (char*)d_ws;
    short* Hb       = (short*)p;           p += (size_t)n * CDIM * sizeof(short);
    float* bufB     = (float*)p;           p += (size_t)n * CDIM * sizeof(float);
    float* alpha_s  = (float*)p;           p += (size_t)n * sizeof(float);
    float* alpha_d  = (float*)p;           p += (size_t)n * sizeof(float);
    float* bnsum    = (float*)p;           p += 512 * sizeof(float);
    short* Wt1      = (short*)p;           p += 128 * 128 * sizeof(short);
    short* Wt2      = (short*)p;           p += 128 * 128 * sizeof(short);
    int*   deg      = (int*)p;             p += (size_t)n * sizeof(int);
    int*   rel      = (int*)p;             p += (size_t)E * sizeof(int);
    int*   offs_raw = (int*)p;             p += (size_t)n * sizeof(int);
    int*   partial  = (int*)p;             p += 128 * sizeof(int);
    int*   offs     = (int*)p;             p += (size_t)(n + 1) * sizeof(int);
    int*   csr      = (int*)p;

    int nb = (n + 1023) / 1024;

    k_setup<<<dim3((n + 255) / 256), dim3(256), 0, stream>>>(deg, bnsum, n, W1, W2, Wt1, Wt2);
    k_count<<<dim3((E + 255) / 256), dim3(256), 0, stream>>>(dst, E, deg, rel);
    k_scan1<<<dim3(nb), dim3(256), 0, stream>>>(deg, offs_raw, partial, n);
    k_scan2<<<dim3(1), dim3(128), 0, stream>>>(partial, nb);
    k_fill<<<dim3((E + n + 255) / 256), dim3(256), 0, stream>>>(src, dst, rel, E, n,
                                                                offs_raw, partial, offs, csr);

    dim3 ggrid((n + 63) / 64);
    dim3 wgrid((n + 3) / 4);

    // layer 1
    k_gemm_mfma<<<ggrid, 256, 0, stream>>>(x, Wt1, nullptr, nullptr, nullptr, invn,
                                           as1, ad1, Hb, alpha_s, alpha_d, n, 0);
    k_agg<<<wgrid, 256, 0, stream>>>((const unsigned*)Hb, offs, csr, alpha_s, alpha_d,
                                     b1, bufB, n);
    k_bnstats<<<dim3(256), dim3(256), 0, stream>>>(bufB, n, bnsum);

    // layer 2 (BN1+relu computed from raw sums inside GEMM2 staging)
    k_gemm_mfma<<<ggrid, 256, 0, stream>>>(bufB, Wt2, bnsum, g1, be1, invn,
                                           as2, ad2, Hb, alpha_s, alpha_d, n, 1);
    k_agg<<<wgrid, 256, 0, stream>>>((const unsigned*)Hb, offs, csr, alpha_s, alpha_d,
                                     b2, bufB, n);
    k_bnstats<<<dim3(256), dim3(256), 0, stream>>>(bufB, n, bnsum + 256);

    // classifier (BN2+relu computed from raw sums inside staging)
    k_cls<<<dim3((n + 127) / 128), dim3(256), 0, stream>>>(bufB, Wc, bc, bnsum + 256,
                                                           g2, be2, invn, out, n);
}

// Round 5
// 549.920 us; speedup vs baseline: 1.6211x; 1.0735x over previous
//
#include <hip/hip_runtime.h>
#include <math.h>

// GAT 2-layer + BN + classifier, MI355X.
// R5: k_agg broadcast via readlane (SGPR source idx + weight, scalar-base
// gather loads); agg output stored as packed bf16 (halves bufB traffic for
// bnstats/GEMM2/cls). 12 launches.

#define CDIM 128
#define NCLS_ 40
#define NEG_SLOPE_ 0.2f
#define BN_EPS_ 1e-5f

using short8  = __attribute__((ext_vector_type(8))) short;
using short4v = __attribute__((ext_vector_type(4))) short;
using f32x4   = __attribute__((ext_vector_type(4))) float;

static __device__ __forceinline__ float lrelu(float a) {
    return a > 0.f ? a : NEG_SLOPE_ * a;
}
// fp32 -> bf16 round-to-nearest-even
static __device__ __forceinline__ short f2bf(float f) {
    unsigned u = __float_as_uint(f);
    u += 0x7fffu + ((u >> 16) & 1u);
    return (short)(u >> 16);
}
static __device__ __forceinline__ float bf_lo(unsigned u) { return __uint_as_float(u << 16); }
static __device__ __forceinline__ float bf_hi(unsigned u) { return __uint_as_float(u & 0xffff0000u); }

// ---------------- setup: deg=1 (self-loop slot 0), bn sums 0, W->bf16^T ----
__global__ void k_setup(int* deg, float* bnsum, int n,
                        const float* __restrict__ W1, const float* __restrict__ W2,
                        short* __restrict__ Wt1, short* __restrict__ Wt2) {
    int i = blockIdx.x * blockDim.x + threadIdx.x;
    if (i < n) deg[i] = 1;
    if (i < 512) bnsum[i] = 0.f;
    if (i < 128 * 128) {
        int k = i >> 7, nn = i & 127;
        Wt1[nn * 128 + k] = f2bf(W1[i]);
        Wt2[nn * 128 + k] = f2bf(W2[i]);
    }
}

// ---------------- degree histogram; rel[e] = slot within dst's segment -----
__global__ void k_count(const int* __restrict__ dst, int E,
                        int* __restrict__ deg, int* __restrict__ rel) {
    int e = blockIdx.x * blockDim.x + threadIdx.x;
    if (e < E) rel[e] = atomicAdd(&deg[dst[e]], 1);
}

// ---------------- exclusive scan (1024-elem chunks) ------------------------
__global__ void k_scan1(const int* __restrict__ deg, int* __restrict__ offs,
                        int* __restrict__ partial, int n) {
    __shared__ int sdata[256];
    int tid = threadIdx.x;
    int base = blockIdx.x * 1024 + tid * 4;
    int v[4]; int s = 0;
    for (int j = 0; j < 4; j++) { int idx = base + j; v[j] = (idx < n) ? deg[idx] : 0; s += v[j]; }
    sdata[tid] = s; __syncthreads();
    for (int d = 1; d < 256; d <<= 1) {
        int t = (tid >= d) ? sdata[tid - d] : 0;
        __syncthreads();
        sdata[tid] += t;
        __syncthreads();
    }
    int excl = sdata[tid] - s;
    if (tid == 255) partial[blockIdx.x] = sdata[255];
    int run = excl;
    for (int j = 0; j < 4; j++) { int idx = base + j; if (idx < n) offs[idx] = run; run += v[j]; }
}

__global__ void k_scan2(int* partial, int nb) {
    __shared__ int sdata[128];
    int t = threadIdx.x;
    int v = (t < nb) ? partial[t] : 0;
    sdata[t] = v; __syncthreads();
    for (int d = 1; d < 128; d <<= 1) {
        int x = (t >= d) ? sdata[t - d] : 0;
        __syncthreads();
        sdata[t] += x;
        __syncthreads();
    }
    if (t < nb) partial[t] = sdata[t] - v;   // exclusive
}

// ---------------- fill: edges (no atomic) + self loops + final offs --------
__global__ void k_fill(const int* __restrict__ src, const int* __restrict__ dst,
                       const int* __restrict__ rel, int E, int n,
                       const int* __restrict__ offs_raw, const int* __restrict__ partial,
                       int* __restrict__ offs_fin, int* __restrict__ csr) {
    int t = blockIdx.x * blockDim.x + threadIdx.x;
    if (t < E) {
        int d = dst[t];
        int p = offs_raw[d] + partial[d >> 10] + rel[t];
        csr[p] = src[t];
    } else if (t < E + n) {
        int i = t - E;
        int base = offs_raw[i] + partial[i >> 10];
        offs_fin[i] = base;
        csr[base] = i;                  // self-loop occupies slot 0
        if (i == 0) offs_fin[n] = E + n;
    }
}

// ---------------- MFMA GEMM: Hb(bf16) = act(X) @ W, alpha fused ------------
// fuse=0: A from fp32 Xf. fuse=1: A from packed-bf16 Xb with BN(raw sums)+relu.
__global__ __launch_bounds__(256) void k_gemm_mfma(
    const float* __restrict__ Xf, const unsigned* __restrict__ Xb,
    const short* __restrict__ Wt,
    const float* __restrict__ bnsum, const float* __restrict__ gamma,
    const float* __restrict__ beta, float invn,
    const float* __restrict__ av_s, const float* __restrict__ av_d,
    short* __restrict__ Hb, float* __restrict__ alpha_s, float* __restrict__ alpha_d,
    int n, int fuse)
{
    __shared__ short As[64 * 128];    // 16.4 KB (reused as H transpose buffer)
    __shared__ short Bs[128 * 128];   // 32.8 KB
    __shared__ float part_s[4][64];
    __shared__ float part_d[4][64];
    int t = threadIdx.x;
    int row0 = blockIdx.x * 64;

    for (int j = 0; j < 8; j++) {
        int idx = j * 256 + t;
        int nn = idx >> 4, cc = idx & 15;
        *(short8*)(Bs + nn * 128 + cc * 8) = *(const short8*)(Wt + nn * 128 + cc * 8);
    }
    // per-thread BN scale/shift for its 4 channels (constant across j)
    float4 sc4 = make_float4(1.f, 1.f, 1.f, 1.f);
    float4 sh4 = make_float4(0.f, 0.f, 0.f, 0.f);
    if (fuse) {
        int cb = (t & 31) * 4;
        float4 s0 = *(const float4*)(bnsum + cb);
        float4 s1 = *(const float4*)(bnsum + 128 + cb);
        float4 gm = *(const float4*)(gamma + cb);
        float4 bt = *(const float4*)(beta + cb);
        float mean, var;
        mean = s0.x * invn; var = fmaxf(s1.x * invn - mean * mean, 0.f);
        sc4.x = gm.x * rsqrtf(var + BN_EPS_); sh4.x = bt.x - mean * sc4.x;
        mean = s0.y * invn; var = fmaxf(s1.y * invn - mean * mean, 0.f);
        sc4.y = gm.y * rsqrtf(var + BN_EPS_); sh4.y = bt.y - mean * sc4.y;
        mean = s0.z * invn; var = fmaxf(s1.z * invn - mean * mean, 0.f);
        sc4.z = gm.z * rsqrtf(var + BN_EPS_); sh4.z = bt.z - mean * sc4.z;
        mean = s0.w * invn; var = fmaxf(s1.w * invn - mean * mean, 0.f);
        sc4.w = gm.w * rsqrtf(var + BN_EPS_); sh4.w = bt.w - mean * sc4.w;
    }
    for (int j = 0; j < 8; j++) {
        int idx = j * 256 + t;
        int r = idx >> 5, k4 = idx & 31;
        int gr = row0 + r;
        float4 xv = make_float4(0.f, 0.f, 0.f, 0.f);
        if (fuse) {
            if (gr < n) {
                uint2 u = *(const uint2*)(Xb + (size_t)gr * 64 + k4 * 2);
                xv.x = bf_lo(u.x); xv.y = bf_hi(u.x);
                xv.z = bf_lo(u.y); xv.w = bf_hi(u.y);
            }
            xv.x = fmaxf(fmaf(xv.x, sc4.x, sh4.x), 0.f);
            xv.y = fmaxf(fmaf(xv.y, sc4.y, sh4.y), 0.f);
            xv.z = fmaxf(fmaf(xv.z, sc4.z, sh4.z), 0.f);
            xv.w = fmaxf(fmaf(xv.w, sc4.w, sh4.w), 0.f);
        } else {
            if (gr < n) xv = *(const float4*)(Xf + (size_t)gr * CDIM + k4 * 4);
        }
        short4v o;
        o.x = f2bf(xv.x); o.y = f2bf(xv.y); o.z = f2bf(xv.z); o.w = f2bf(xv.w);
        *(short4v*)(As + r * 128 + k4 * 4) = o;
    }
    __syncthreads();

    int w = t >> 6, lane = t & 63, q = lane >> 4, c = lane & 15;
    f32x4 zero = {0.f, 0.f, 0.f, 0.f};
    f32x4 acc[4][2];
    for (int i = 0; i < 4; i++) { acc[i][0] = zero; acc[i][1] = zero; }

    for (int ks = 0; ks < 4; ks++) {
        int k0 = ks * 32 + q * 8;
        short8 a0 = *(short8*)(As + (c) * 128 + k0);
        short8 a1 = *(short8*)(As + (16 + c) * 128 + k0);
        short8 a2 = *(short8*)(As + (32 + c) * 128 + k0);
        short8 a3 = *(short8*)(As + (48 + c) * 128 + k0);
        short8 b0 = *(short8*)(Bs + (w * 32 + c) * 128 + k0);
        short8 b1 = *(short8*)(Bs + (w * 32 + 16 + c) * 128 + k0);
        acc[0][0] = __builtin_amdgcn_mfma_f32_16x16x32_bf16(a0, b0, acc[0][0], 0, 0, 0);
        acc[1][0] = __builtin_amdgcn_mfma_f32_16x16x32_bf16(a1, b0, acc[1][0], 0, 0, 0);
        acc[2][0] = __builtin_amdgcn_mfma_f32_16x16x32_bf16(a2, b0, acc[2][0], 0, 0, 0);
        acc[3][0] = __builtin_amdgcn_mfma_f32_16x16x32_bf16(a3, b0, acc[3][0], 0, 0, 0);
        acc[0][1] = __builtin_amdgcn_mfma_f32_16x16x32_bf16(a0, b1, acc[0][1], 0, 0, 0);
        acc[1][1] = __builtin_amdgcn_mfma_f32_16x16x32_bf16(a1, b1, acc[1][1], 0, 0, 0);
        acc[2][1] = __builtin_amdgcn_mfma_f32_16x16x32_bf16(a2, b1, acc[2][1], 0, 0, 0);
        acc[3][1] = __builtin_amdgcn_mfma_f32_16x16x32_bf16(a3, b1, acc[3][1], 0, 0, 0);
    }

    float as0 = av_s[w * 32 + c],      as1 = av_s[w * 32 + 16 + c];
    float ad0 = av_d[w * 32 + c],      ad1 = av_d[w * 32 + 16 + c];
    #pragma unroll
    for (int mt = 0; mt < 4; mt++) {
        #pragma unroll
        for (int r = 0; r < 4; r++) {
            float v0 = acc[mt][0][r], v1 = acc[mt][1][r];
            float ps = v0 * as0 + v1 * as1;
            float pd = v0 * ad0 + v1 * ad1;
            #pragma unroll
            for (int off = 1; off < 16; off <<= 1) {
                ps += __shfl_xor(ps, off);
                pd += __shfl_xor(pd, off);
            }
            if (c == 0) {
                part_s[w][mt * 16 + q * 4 + r] = ps;
                part_d[w][mt * 16 + q * 4 + r] = pd;
            }
        }
    }
    __syncthreads();

    short* Hs = As;
    #pragma unroll
    for (int mt = 0; mt < 4; mt++)
        #pragma unroll
        for (int nt = 0; nt < 2; nt++)
            #pragma unroll
            for (int r = 0; r < 4; r++)
                Hs[(mt * 16 + q * 4 + r) * 128 + w * 32 + nt * 16 + c] = f2bf(acc[mt][nt][r]);

    if (t < 64) {
        int row = row0 + t;
        if (row < n) {
            alpha_s[row] = part_s[0][t] + part_s[1][t] + part_s[2][t] + part_s[3][t];
            alpha_d[row] = part_d[0][t] + part_d[1][t] + part_d[2][t] + part_d[3][t];
        }
    }
    __syncthreads();

    for (int j = 0; j < 4; j++) {
        int idx = j * 256 + t;
        int r = idx >> 4, cc = idx & 15;
        int gr = row0 + r;
        if (gr < n)
            *(short8*)(Hb + (size_t)gr * 128 + cc * 8) = *(short8*)(Hs + r * 128 + cc * 8);
    }
}

// ---------------- ONE-PASS softmax + aggregation (one wave per node) -------
// Broadcasts via readlane (index is wave-uniform): source idx + weight land
// in SGPRs -> scalar-base gather loads, SGPR-operand FMAs. Output packed bf16.
__global__ __launch_bounds__(256) void k_agg(
    const unsigned* __restrict__ Hb, const int* __restrict__ offs,
    const int* __restrict__ csr, const float* __restrict__ alpha_s,
    const float* __restrict__ alpha_d, const float* __restrict__ bias,
    unsigned* __restrict__ Ob, int n)
{
    int i = blockIdx.x * 4 + (threadIdx.x >> 6);
    int lane = threadIdx.x & 63;
    if (i >= n) return;
    int o0 = offs[i], o1 = offs[i + 1];
    float adi = alpha_d[i];

    float m = -1e30f;
    float se = 0.f;
    float ax = 0.f, ay = 0.f;

    for (int c0 = o0; c0 < o1; c0 += 64) {
        int j = c0 + lane;
        int cnt = min(64, o1 - c0);
        int sj = (j < o1) ? csr[j] : 0;
        float a = (j < o1) ? lrelu(alpha_s[sj] + adi) : -1e30f;

        float cm = a;
        #pragma unroll
        for (int o = 32; o > 0; o >>= 1) cm = fmaxf(cm, __shfl_xor(cm, o));
        if (cm > m) {
            float r = __expf(m - cm);
            se *= r; ax *= r; ay *= r;
            m = cm;
        }
        float wl = (j < o1) ? __expf(a - m) : 0.f;
        se += wl;
        unsigned wlb = __float_as_uint(wl);

        for (int b = 0; b < cnt; b += 8) {
            unsigned u[8]; float wv[8];
            #pragma unroll
            for (int q2 = 0; q2 < 8; q2++) {
                int e = b + q2;
                int el = (e < cnt) ? e : (cnt - 1);          // wave-uniform
                int s = __builtin_amdgcn_readlane(sj, el);   // SGPR
                unsigned wb = __builtin_amdgcn_readlane(wlb, el);
                wv[q2] = (e < cnt) ? __uint_as_float(wb) : 0.f;
                u[q2] = Hb[(size_t)(unsigned)s * 64 + lane]; // scalar base + lane off
            }
            #pragma unroll
            for (int q2 = 0; q2 < 8; q2++) {
                ax = fmaf(wv[q2], bf_lo(u[q2]), ax);
                ay = fmaf(wv[q2], bf_hi(u[q2]), ay);
            }
        }
    }

    #pragma unroll
    for (int o = 32; o > 0; o >>= 1) se += __shfl_xor(se, o);
    float inv = 1.f / se;
    float2 b2 = *(const float2*)(bias + lane * 2);
    float rx = fmaf(ax, inv, b2.x);
    float ry = fmaf(ay, inv, b2.y);
    unsigned pack = ((unsigned)(unsigned short)f2bf(ry) << 16) |
                    (unsigned)(unsigned short)f2bf(rx);
    Ob[(size_t)i * 64 + lane] = pack;
}

// ---------------- BN stats from packed bf16: per-channel sum / sumsq -------
__global__ void k_bnstats(const unsigned* __restrict__ Hb, int n, float* __restrict__ sums) {
    __shared__ float red[4][64][4];
    int w = threadIdx.x & 63;
    int g = threadIdx.x >> 6;
    float slo = 0.f, shi = 0.f, qlo = 0.f, qhi = 0.f;
    for (int r = blockIdx.x * 4 + g; r < n; r += gridDim.x * 4) {
        unsigned u = Hb[(size_t)r * 64 + w];
        float lo = bf_lo(u), hi = bf_hi(u);
        slo += lo; shi += hi; qlo += lo * lo; qhi += hi * hi;
    }
    red[g][w][0] = slo; red[g][w][1] = shi; red[g][w][2] = qlo; red[g][w][3] = qhi;
    __syncthreads();
    if (threadIdx.x < 64) {
        int w2 = threadIdx.x;
        float a0 = 0.f, a1 = 0.f, a2 = 0.f, a3 = 0.f;
        for (int gg = 0; gg < 4; gg++) {
            a0 += red[gg][w2][0]; a1 += red[gg][w2][1];
            a2 += red[gg][w2][2]; a3 += red[gg][w2][3];
        }
        atomicAdd(&sums[2 * w2], a0);
        atomicAdd(&sums[2 * w2 + 1], a1);
        atomicAdd(&sums[128 + 2 * w2], a2);
        atomicAdd(&sums[128 + 2 * w2 + 1], a3);
    }
}

// ---------------- classifier: out = relu(bn(G)) @ Wc + bc ------------------
#define CLS_XS_LD 129
__global__ __launch_bounds__(256) void k_cls(
    const unsigned* __restrict__ G, const float* __restrict__ Wc,
    const float* __restrict__ bc, const float* __restrict__ bnsum,
    const float* __restrict__ gamma, const float* __restrict__ beta, float invn,
    float* __restrict__ out, int n)
{
    __shared__ float Xs[128 * CLS_XS_LD];   // 66.0 KB
    __shared__ float Ws[128 * NCLS_];       // 20.5 KB
    int t = threadIdx.x;
    int row0 = blockIdx.x * 128;

    for (int j = 0; j < 20; j++) Ws[j * 256 + t] = Wc[j * 256 + t];

    float4 sc4, sh4;
    {
        int cb = (t & 31) * 4;
        float4 s0 = *(const float4*)(bnsum + cb);
        float4 s1 = *(const float4*)(bnsum + 128 + cb);
        float4 gm = *(const float4*)(gamma + cb);
        float4 bt = *(const float4*)(beta + cb);
        float mean, var;
        mean = s0.x * invn; var = fmaxf(s1.x * invn - mean * mean, 0.f);
        sc4.x = gm.x * rsqrtf(var + BN_EPS_); sh4.x = bt.x - mean * sc4.x;
        mean = s0.y * invn; var = fmaxf(s1.y * invn - mean * mean, 0.f);
        sc4.y = gm.y * rsqrtf(var + BN_EPS_); sh4.y = bt.y - mean * sc4.y;
        mean = s0.z * invn; var = fmaxf(s1.z * invn - mean * mean, 0.f);
        sc4.z = gm.z * rsqrtf(var + BN_EPS_); sh4.z = bt.z - mean * sc4.z;
        mean = s0.w * invn; var = fmaxf(s1.w * invn - mean * mean, 0.f);
        sc4.w = gm.w * rsqrtf(var + BN_EPS_); sh4.w = bt.w - mean * sc4.w;
    }
    for (int j = 0; j < 16; j++) {
        int idx = j * 256 + t;
        int r = idx >> 5, k4 = idx & 31;
        int gr = row0 + r;
        float4 xv = make_float4(0.f, 0.f, 0.f, 0.f);
        if (gr < n) {
            uint2 u = *(const uint2*)(G + (size_t)gr * 64 + k4 * 2);
            xv.x = bf_lo(u.x); xv.y = bf_hi(u.x);
            xv.z = bf_lo(u.y); xv.w = bf_hi(u.y);
        }
        float* xp = Xs + r * CLS_XS_LD + k4 * 4;
        xp[0] = fmaxf(fmaf(xv.x, sc4.x, sh4.x), 0.f);
        xp[1] = fmaxf(fmaf(xv.y, sc4.y, sh4.y), 0.f);
        xp[2] = fmaxf(fmaf(xv.z, sc4.z, sh4.z), 0.f);
        xp[3] = fmaxf(fmaf(xv.w, sc4.w, sh4.w), 0.f);
    }
    __syncthreads();

    int cg = t & 3;
    int r0 = t >> 2;
    float acc[2][10] = {};
    for (int k = 0; k < CDIM; k++) {
        float x0 = Xs[(r0 * 2 + 0) * CLS_XS_LD + k];
        float x1 = Xs[(r0 * 2 + 1) * CLS_XS_LD + k];
        #pragma unroll
        for (int j = 0; j < 10; j++) {
            float w = Ws[k * NCLS_ + cg * 10 + j];
            acc[0][j] = fmaf(x0, w, acc[0][j]);
            acc[1][j] = fmaf(x1, w, acc[1][j]);
        }
    }
    for (int i = 0; i < 2; i++) {
        int gr = row0 + r0 * 2 + i;
        if (gr < n) {
            #pragma unroll
            for (int j = 0; j < 10; j++)
                out[(size_t)gr * NCLS_ + cg * 10 + j] = acc[i][j] + bc[cg * 10 + j];
        }
    }
}

// ---------------- launch ---------------------------------------------------
extern "C" void kernel_launch(void* const* d_in, const int* in_sizes, int n_in,
                              void* d_out, int out_size, void* d_ws, size_t ws_size,
                              hipStream_t stream)
{
    const float* x   = (const float*)d_in[0];
    const int*   ei  = (const int*)d_in[1];
    const float* W1  = (const float*)d_in[2];
    const float* as1 = (const float*)d_in[3];
    const float* ad1 = (const float*)d_in[4];
    const float* b1  = (const float*)d_in[5];
    const float* g1  = (const float*)d_in[6];
    const float* be1 = (const float*)d_in[7];
    const float* W2  = (const float*)d_in[8];
    const float* as2 = (const float*)d_in[9];
    const float* ad2 = (const float*)d_in[10];
    const float* b2  = (const float*)d_in[11];
    const float* g2  = (const float*)d_in[12];
    const float* be2 = (const float*)d_in[13];
    const float* Wc  = (const float*)d_in[14];
    const float* bc  = (const float*)d_in[15];
    float* out = (float*)d_out;

    int n = in_sizes[0] / CDIM;     // 100000
    int E = in_sizes[1] / 2;        // 1600000
    const int* src = ei;
    const int* dst = ei + E;
    float invn = 1.f / (float)n;

    // workspace layout
    char* p = (char*)d_ws;
    short*    Hb       = (short*)p;        p += (size_t)n * CDIM * sizeof(short);
    unsigned* bufB     = (unsigned*)p;     p += (size_t)n * 64 * sizeof(unsigned);
    float*    alpha_s  = (float*)p;        p += (size_t)n * sizeof(float);
    float*    alpha_d  = (float*)p;        p += (size_t)n * sizeof(float);
    float*    bnsum    = (float*)p;        p += 512 * sizeof(float);
    short*    Wt1      = (short*)p;        p += 128 * 128 * sizeof(short);
    short*    Wt2      = (short*)p;        p += 128 * 128 * sizeof(short);
    int*      deg      = (int*)p;          p += (size_t)n * sizeof(int);
    int*      rel      = (int*)p;          p += (size_t)E * sizeof(int);
    int*      offs_raw = (int*)p;          p += (size_t)n * sizeof(int);
    int*      partial  = (int*)p;          p += 128 * sizeof(int);
    int*      offs     = (int*)p;          p += (size_t)(n + 1) * sizeof(int);
    int*      csr      = (int*)p;

    int nb = (n + 1023) / 1024;

    k_setup<<<dim3((n + 255) / 256), dim3(256), 0, stream>>>(deg, bnsum, n, W1, W2, Wt1, Wt2);
    k_count<<<dim3((E + 255) / 256), dim3(256), 0, stream>>>(dst, E, deg, rel);
    k_scan1<<<dim3(nb), dim3(256), 0, stream>>>(deg, offs_raw, partial, n);
    k_scan2<<<dim3(1), dim3(128), 0, stream>>>(partial, nb);
    k_fill<<<dim3((E + n + 255) / 256), dim3(256), 0, stream>>>(src, dst, rel, E, n,
                                                                offs_raw, partial, offs, csr);

    dim3 ggrid((n + 63) / 64);
    dim3 wgrid((n + 3) / 4);

    // layer 1
    k_gemm_mfma<<<ggrid, 256, 0, stream>>>(x, nullptr, Wt1, nullptr, nullptr, nullptr,
                                           invn, as1, ad1, Hb, alpha_s, alpha_d, n, 0);
    k_agg<<<wgrid, 256, 0, stream>>>((const unsigned*)Hb, offs, csr, alpha_s, alpha_d,
                                     b1, bufB, n);
    k_bnstats<<<dim3(256), dim3(256), 0, stream>>>(bufB, n, bnsum);

    // layer 2 (BN1+relu from raw sums inside GEMM2 staging, bf16 input)
    k_gemm_mfma<<<ggrid, 256, 0, stream>>>(nullptr, bufB, Wt2, bnsum, g1, be1,
                                           invn, as2, ad2, Hb, alpha_s, alpha_d, n, 1);
    k_agg<<<wgrid, 256, 0, stream>>>((const unsigned*)Hb, offs, csr, alpha_s, alpha_d,
                                     b2, bufB, n);
    k_bnstats<<<dim3(256), dim3(256), 0, stream>>>(bufB, n, bnsum + 256);

    // classifier (BN2+relu from raw sums inside staging, bf16 input)
    k_cls<<<dim3((n + 127) / 128), dim3(256), 0, stream>>>(bufB, Wc, bc, bnsum + 256,
                                                           g2, be2, invn, out, n);
}